// Round 17
// baseline (2182.172 us; speedup 1.0000x reference)
//
#include <hip/hip_runtime.h>
#include <hip/hip_bf16.h>

#define DI __device__ __forceinline__

typedef unsigned short u16;
typedef __bf16 bf16x8 __attribute__((ext_vector_type(8)));
typedef unsigned short u16x8 __attribute__((ext_vector_type(8)));
typedef unsigned short u16x4 __attribute__((ext_vector_type(4)));
typedef float f32x4 __attribute__((ext_vector_type(4)));

static constexpr int Bb = 8, Tt = 256, Hh = 1024, Ll = 6, NHd = 16, Dh = 64;
static constexpr int Ss = 3 * Tt;      // 768 tokens
static constexpr int FFd = 4096;
static constexpr int BSr = Bb * Ss;    // 6144 rows
static constexpr int QKVld = 3072;     // fused qkv row stride

DI u16 f2bf(float f) {
  unsigned u = __builtin_bit_cast(unsigned, f);
  u += 0x7fffu + ((u >> 16) & 1u);
  return (u16)(u >> 16);
}

// tanh-form GELU (max |diff| vs erf-GELU ~3e-3, well under 7e-2 threshold)
DI float gelu_f(float x) {
  const float s = 1.5957691216f * x + 0.0713564814f * x * x * x;
  return x / (1.f + __expf(-s));
}

DI void gload_lds16(const u16* g, u16* l) {
  __builtin_amdgcn_global_load_lds((__attribute__((address_space(1))) void*)(g),
                                   (__attribute__((address_space(3))) void*)(l), 16, 0, 0);
}
DI bf16x8 ldl8(const u16* p) { return __builtin_bit_cast(bf16x8, *(const u16x8*)p); }
DI bf16x8 ldg8(const u16* p) { return __builtin_bit_cast(bf16x8, *(const u16x8*)p); }

DI void barRaw() {
  asm volatile("" ::: "memory");
  __builtin_amdgcn_s_barrier();
  asm volatile("" ::: "memory");
}

// ---------------------------------------------------------------------------
// GEMM: 128x128 tile, BK=64, 4 waves, double-buffered LDS (64 KiB, 2/CU).
// K-loop unrolled x2 with static buffer bases (R15); coalesced LDS-staged
// epilogue (R12); 2D-patch XCD swizzle (R13); tanh-GELU (R15).
// Optional split-K via blockIdx.z writing fp32 partials at outf + z*psz.
// ---------------------------------------------------------------------------
__global__ __launch_bounds__(256, 2) void gemm_db(
    const u16* __restrict__ A, const u16* __restrict__ Bt,
    const float* __restrict__ bias, const float* __restrict__ bias2,
    const float* __restrict__ bias3,
    float* __restrict__ outf, u16* __restrict__ outb,
    int Kstride, int Ksub, int ldc, int act, size_t psz)
{
  __shared__ u16 SM[32768];   // 64 KiB: A0@0, A1@8192, B0@16384, B1@24576
  const int lane = threadIdx.x & 63, w = threadIdx.x >> 6;
  const int wr = w >> 1, wc = w & 1;
  const int l15 = lane & 15, l4 = lane >> 4;

  // bijective XCD swizzle (m204) + 2D patch mapping (CG=8 cols, bn fastest)
  const int gx = gridDim.x, gy = gridDim.y, nwg = gx * gy;
  int f = blockIdx.y * gx + blockIdx.x;
  { int q = nwg >> 3, rr = nwg & 7, x = f & 7, idx = f >> 3;
    f = (x < rr ? x * (q + 1) : rr * (q + 1) + (x - rr) * q) + idx; }
  const int r2 = f % (gy * 8), cg = f / (gy * 8);
  const int bm = r2 >> 3, bn = cg * 8 + (r2 & 7);
  const int koff = blockIdx.z * Ksub;
  const int NT = Ksub >> 6;   // even for all uses (16 / 32 / 8)

  const int srow = lane >> 3;
  const int schunk = ((lane & 7) ^ srow) << 3;
  unsigned aoff[4], boff[4];
#pragma unroll
  for (int i = 0; i < 4; ++i) {
    const int r = w * 32 + i * 8 + srow;
    aoff[i] = (unsigned)(bm * 128 + r) * (unsigned)Kstride + koff + schunk;
    boff[i] = (unsigned)(bn * 128 + r) * (unsigned)Kstride + koff + schunk;
  }

  auto stage = [&](int bsel, int kt) {
#pragma unroll
    for (int i = 0; i < 4; ++i)
      gload_lds16(A + aoff[i] + kt * 64, &SM[bsel * 8192 + (w * 32 + i * 8) * 64]);
#pragma unroll
    for (int i = 0; i < 4; ++i)
      gload_lds16(Bt + boff[i] + kt * 64, &SM[16384 + bsel * 8192 + (w * 32 + i * 8) * 64]);
  };

  f32x4 acc[4][4] = {};
  const int r7 = l15 & 7;

  auto body = [&](int CB, int tn, bool more) {
    if (more) stage(CB ^ 1, tn);
    bf16x8 af[4][2], bf[4][2];
#pragma unroll
    for (int m = 0; m < 4; ++m) {
#pragma unroll
      for (int kk = 0; kk < 2; ++kk) {
        const int slot = (((kk * 4 + l4) ^ r7) << 3);
        af[m][kk] = ldl8(&SM[CB * 8192 + (wr * 64 + m * 16 + l15) * 64 + slot]);
        bf[m][kk] = ldl8(&SM[16384 + CB * 8192 + (wc * 64 + m * 16 + l15) * 64 + slot]);
      }
    }
    __builtin_amdgcn_s_setprio(1);
#pragma unroll
    for (int kk = 0; kk < 2; ++kk)
#pragma unroll
      for (int m = 0; m < 4; ++m)
#pragma unroll
        for (int n = 0; n < 4; ++n)
          acc[m][n] = __builtin_amdgcn_mfma_f32_16x16x32_bf16(af[m][kk], bf[n][kk], acc[m][n], 0, 0, 0);
    __builtin_amdgcn_s_setprio(0);
    if (more) asm volatile("s_waitcnt vmcnt(0)" ::: "memory");  // aged drain
    barRaw();
  };

  stage(0, 0);
  asm volatile("s_waitcnt vmcnt(0)" ::: "memory");
  barRaw();

  for (int t = 0; t < NT; t += 2) {
    body(0, t + 1, t + 1 < NT);
    body(1, t + 2, t + 2 < NT);
  }

  // ---- coalesced epilogue via LDS staging ----
  if (outb) {
#pragma unroll
    for (int n = 0; n < 4; ++n) {
      const int col = wc * 64 + n * 16 + l15;
      const int gcol = bn * 128 + col;
      float bval = 0.f;
      if (bias) {
        const float* bp_ = bias;
        int idx = gcol;
        if (bias2 && gcol >= 1024) { bp_ = (gcol >= 2048) ? bias3 : bias2; idx = gcol & 1023; }
        bval = bp_[idx];
      }
#pragma unroll
      for (int m = 0; m < 4; ++m) {
#pragma unroll
        for (int r = 0; r < 4; ++r) {
          const int lrow = wr * 64 + m * 16 + l4 * 4 + r;
          float x = acc[m][n][r] + bval;
          if (act) x = gelu_f(x);
          SM[lrow * 128 + col] = f2bf(x);
        }
      }
    }
    barRaw();
#pragma unroll 4
    for (int rr2 = 0; rr2 < 32; ++rr2) {
      const int row = rr2 * 4 + w;
      *(unsigned*)&outb[(size_t)(bm * 128 + row) * ldc + bn * 128 + lane * 2] =
          *(const unsigned*)&SM[row * 128 + lane * 2];
    }
  } else if (outf) {
    float* Cf = (float*)SM;
#pragma unroll
    for (int half = 0; half < 2; ++half) {
      barRaw();
      if (wr == half) {
#pragma unroll
        for (int n = 0; n < 4; ++n) {
          const int col = wc * 64 + n * 16 + l15;
          const int gcol = bn * 128 + col;
          float bval = 0.f;
          if (bias) {
            const float* bp_ = bias;
            int idx = gcol;
            if (bias2 && gcol >= 1024) { bp_ = (gcol >= 2048) ? bias3 : bias2; idx = gcol & 1023; }
            bval = bp_[idx];
          }
#pragma unroll
          for (int m = 0; m < 4; ++m) {
#pragma unroll
            for (int r = 0; r < 4; ++r) {
              float x = acc[m][n][r] + bval;
              if (act) x = gelu_f(x);
              Cf[(m * 16 + l4 * 4 + r) * 128 + col] = x;
            }
          }
        }
      }
      barRaw();
#pragma unroll 4
      for (int rr2 = 0; rr2 < 16; ++rr2) {
        const int row = rr2 * 4 + w;
        *(float2*)&outf[blockIdx.z * psz +
                        (size_t)(bm * 128 + half * 64 + row) * ldc + bn * 128 + lane * 2] =
            *(const float2*)&Cf[row * 128 + lane * 2];
      }
    }
  }
}

// ---------------------------------------------------------------------------
// Small GEMM (heads): 128x128 tile, BK=64, 4 waves, 16x16 MFMA.
// ---------------------------------------------------------------------------
__global__ __launch_bounds__(256, 2) void gemm_bf16(
    const u16* __restrict__ A, const u16* __restrict__ Bt,
    const float* __restrict__ bias, float* __restrict__ outf,
    int M, int N, int K, int ldc, int Nstore, int rowmode, int rowoff)
{
  __shared__ u16 As[128 * 64];
  __shared__ u16 Bs[128 * 64];
  const int tid = threadIdx.x;
  const int lane = tid & 63;
  const int w = tid >> 6;
  const int wr = w >> 1, wc = w & 1;
  const int bn = blockIdx.x, bm = blockIdx.y;
  const int l3 = lane >> 3, l7 = lane & 7, l15 = lane & 15, l4 = lane >> 4;

  f32x4 acc[4][4] = {};

  const int schunk = (l7 ^ l3) << 3;
  size_t aoff[4], boff[4];
#pragma unroll
  for (int i = 0; i < 4; ++i) {
    int r = bm * 128 + w * 32 + i * 8 + l3;
    int ar = rowmode ? ((r >> 8) * Ss + rowoff + (r & 255)) : r;
    aoff[i] = (size_t)ar * K + schunk;
    boff[i] = (size_t)(bn * 128 + w * 32 + i * 8 + l3) * K + schunk;
  }

  for (int kt = 0; kt < K; kt += 64) {
    __syncthreads();
#pragma unroll
    for (int i = 0; i < 4; ++i) {
      gload_lds16(A + aoff[i] + kt, &As[(w * 32 + i * 8) * 64]);
      gload_lds16(Bt + boff[i] + kt, &Bs[(w * 32 + i * 8) * 64]);
    }
    __syncthreads();

    bf16x8 af[4][2], bf[4][2];
#pragma unroll
    for (int m = 0; m < 4; ++m) {
#pragma unroll
      for (int kk = 0; kk < 2; ++kk) {
        const int slot = ((kk * 4 + l4) ^ l7) << 3;
        af[m][kk] = ldl8(&As[(wr * 64 + m * 16 + l15) * 64 + slot]);
        bf[m][kk] = ldl8(&Bs[(wc * 64 + m * 16 + l15) * 64 + slot]);
      }
    }
#pragma unroll
    for (int m = 0; m < 4; ++m)
#pragma unroll
      for (int n = 0; n < 4; ++n)
#pragma unroll
        for (int kk = 0; kk < 2; ++kk)
          acc[m][n] = __builtin_amdgcn_mfma_f32_16x16x32_bf16(af[m][kk], bf[n][kk], acc[m][n], 0, 0, 0);
  }

#pragma unroll
  for (int n = 0; n < 4; ++n) {
    const int col = bn * 128 + wc * 64 + n * 16 + l15;
    const bool cok = col < Nstore;
    const float bv = (cok && bias) ? bias[col] : 0.f;
#pragma unroll
    for (int m = 0; m < 4; ++m) {
#pragma unroll
      for (int r = 0; r < 4; ++r) {
        const int row = bm * 128 + wr * 64 + m * 16 + l4 * 4 + r;
        if (cok) outf[(size_t)row * ldc + col] = acc[m][n][r] + bv;
      }
    }
  }
}

// ---------------------------------------------------------------------------
// Flash attention (unchanged)
// ---------------------------------------------------------------------------
__global__ __launch_bounds__(256, 3) void attn_flash(
    const u16* __restrict__ qkv, const u16* __restrict__ vt, u16* __restrict__ o)
{
  __shared__ u16 Kl[2][64 * 64];
  __shared__ u16 Vl[2][64 * 64];
  __shared__ u16 Pl[4][16 * 64];
  const int qt = blockIdx.x, h = blockIdx.y, b = blockIdx.z;
  const int lane = threadIdx.x & 63, w = threadIdx.x >> 6;
  const int l15 = lane & 15, l4 = lane >> 4;

  const size_t qoff = (size_t)(b * Ss + qt * 64 + w * 16 + l15) * QKVld + h * Dh + l4 * 8;
  const bf16x8 aq0 = ldg8(qkv + qoff), aq1 = ldg8(qkv + qoff + 32);

  const u16* kg = qkv + (size_t)b * Ss * QKVld + 1024 + h * Dh;
  const u16* vg = vt + (size_t)(b * NHd + h) * Dh * Ss;

  int srow[2], scs[2];
#pragma unroll
  for (int i = 0; i < 2; ++i) {
    srow[i] = (w * 2 + i) * 8 + (lane >> 3);
    scs[i] = ((lane & 7) ^ (srow[i] & 7)) * 8;
  }

  float m[4] = {-1e30f, -1e30f, -1e30f, -1e30f};
  float lsum[4] = {0.f, 0.f, 0.f, 0.f};
  f32x4 oa[4] = {};

  auto stage = [&](int bsel, int kb) {
#pragma unroll
    for (int i = 0; i < 2; ++i) {
      gload_lds16(kg + (size_t)(kb * 64 + srow[i]) * QKVld + scs[i], &Kl[bsel][(w * 2 + i) * 8 * 64]);
      gload_lds16(vg + (size_t)srow[i] * Ss + kb * 64 + scs[i], &Vl[bsel][(w * 2 + i) * 8 * 64]);
    }
  };

  stage(0, 0);
  __syncthreads();
  int buf = 0;
  for (int kb = 0; kb <= qt; ++kb) {
    if (kb < qt) stage(buf ^ 1, kb + 1);

    f32x4 sc[4];
    __builtin_amdgcn_s_setprio(1);
#pragma unroll
    for (int fj = 0; fj < 4; ++fj) {
      const u16* kp = &Kl[buf][(fj * 16 + l15) * 64];
      const int r7 = l15 & 7;
      bf16x8 kf0 = ldl8(kp + ((l4 ^ r7) << 3));
      bf16x8 kf1 = ldl8(kp + (((4 + l4) ^ r7) << 3));
      f32x4 zz = {};
      zz = __builtin_amdgcn_mfma_f32_16x16x32_bf16(aq0, kf0, zz, 0, 0, 0);
      sc[fj] = __builtin_amdgcn_mfma_f32_16x16x32_bf16(aq1, kf1, zz, 0, 0, 0);
    }
    __builtin_amdgcn_s_setprio(0);

    float pm[4] = {-1e30f, -1e30f, -1e30f, -1e30f};
    const bool diag = (kb == qt);
#pragma unroll
    for (int fj = 0; fj < 4; ++fj)
#pragma unroll
      for (int r = 0; r < 4; ++r) {
        float s = sc[fj][r] * 0.125f;
        if (diag && (fj * 16 + l15) > (w * 16 + l4 * 4 + r)) s = -1e30f;
        sc[fj][r] = s;
        pm[r] = fmaxf(pm[r], s);
      }
#pragma unroll
    for (int d = 1; d < 16; d <<= 1)
#pragma unroll
      for (int r = 0; r < 4; ++r) pm[r] = fmaxf(pm[r], __shfl_xor(pm[r], d));

    float al[4], ps[4];
#pragma unroll
    for (int r = 0; r < 4; ++r) {
      float mn = fmaxf(m[r], pm[r]);
      al[r] = __expf(m[r] - mn);
      m[r] = mn;
      ps[r] = 0.f;
    }
#pragma unroll
    for (int fj = 0; fj < 4; ++fj)
#pragma unroll
      for (int r = 0; r < 4; ++r) {
        float p = __expf(sc[fj][r] - m[r]);
        sc[fj][r] = p;
        ps[r] += p;
      }
#pragma unroll
    for (int d = 1; d < 16; d <<= 1)
#pragma unroll
      for (int r = 0; r < 4; ++r) ps[r] += __shfl_xor(ps[r], d);
#pragma unroll
    for (int r = 0; r < 4; ++r) lsum[r] = lsum[r] * al[r] + ps[r];
#pragma unroll
    for (int fn = 0; fn < 4; ++fn)
#pragma unroll
      for (int r = 0; r < 4; ++r) oa[fn][r] *= al[r];

#pragma unroll
    for (int fj = 0; fj < 4; ++fj)
#pragma unroll
      for (int r = 0; r < 4; ++r) {
        const int key = fj * 16 + l15, qloc = l4 * 4 + r;
        Pl[w][qloc * 64 + (((key >> 3) ^ (qloc & 7)) << 3) + (key & 7)] = f2bf(sc[fj][r]);
      }

    const int q7 = l15 & 7;
    bf16x8 pa0 = ldl8(&Pl[w][l15 * 64 + ((l4 ^ q7) << 3)]);
    bf16x8 pa1 = ldl8(&Pl[w][l15 * 64 + (((4 + l4) ^ q7) << 3)]);
    __builtin_amdgcn_s_setprio(1);
#pragma unroll
    for (int fn = 0; fn < 4; ++fn) {
      const u16* vp = &Vl[buf][(fn * 16 + l15) * 64];
      bf16x8 vf0 = ldl8(vp + ((l4 ^ q7) << 3));
      bf16x8 vf1 = ldl8(vp + (((4 + l4) ^ q7) << 3));
      oa[fn] = __builtin_amdgcn_mfma_f32_16x16x32_bf16(pa0, vf0, oa[fn], 0, 0, 0);
      oa[fn] = __builtin_amdgcn_mfma_f32_16x16x32_bf16(pa1, vf1, oa[fn], 0, 0, 0);
    }
    __builtin_amdgcn_s_setprio(0);
    __syncthreads();
    buf ^= 1;
  }

#pragma unroll
  for (int fn = 0; fn < 4; ++fn)
#pragma unroll
    for (int r = 0; r < 4; ++r) {
      const int row = b * Ss + qt * 64 + w * 16 + l4 * 4 + r;
      o[(size_t)row * Hh + h * Dh + fn * 16 + l15] = f2bf(oa[fn][r] / lsum[r]);
    }
}

// ---------------------------------------------------------------------------
// Embedding + interleave + LayerNorm -> h (fp32) and x (bf16)
// ---------------------------------------------------------------------------
__global__ __launch_bounds__(256) void embed_ln(
    const int* __restrict__ timesteps, const int* __restrict__ states,
    const int* __restrict__ actions, const float* __restrict__ rtg,
    const float* __restrict__ Wt, const float* __restrict__ Ws,
    const float* __restrict__ Wa, const float* __restrict__ Wr,
    const float* __restrict__ br, const float* __restrict__ lng,
    const float* __restrict__ lnb, float* __restrict__ hout, u16* __restrict__ xb)
{
  __shared__ float red[8];
  const int s = blockIdx.x;
  const int b = s / Ss, sl = s % Ss;
  const int tt = sl / 3, kind = sl % 3;
  const int bt = b * Tt + tt;
  const int e = threadIdx.x * 4;

  const float4 tv = *(const float4*)(Wt + (size_t)timesteps[bt] * Hh + e);
  float v[4];
  if (kind == 0) {
    const float rr = rtg[bt];
    const float4 w4 = *(const float4*)(Wr + e);
    const float4 b4 = *(const float4*)(br + e);
    v[0] = rr * w4.x + b4.x + tv.x; v[1] = rr * w4.y + b4.y + tv.y;
    v[2] = rr * w4.z + b4.z + tv.z; v[3] = rr * w4.w + b4.w + tv.w;
  } else {
    const float* emb = (kind == 1) ? (Ws + (size_t)states[bt] * Hh)
                                   : (Wa + (size_t)actions[bt] * Hh);
    const float4 e4 = *(const float4*)(emb + e);
    v[0] = e4.x + tv.x; v[1] = e4.y + tv.y; v[2] = e4.z + tv.z; v[3] = e4.w + tv.w;
  }
  float s1 = v[0] + v[1] + v[2] + v[3];
  float s2 = v[0]*v[0] + v[1]*v[1] + v[2]*v[2] + v[3]*v[3];
#pragma unroll
  for (int d = 32; d; d >>= 1) { s1 += __shfl_xor(s1, d); s2 += __shfl_xor(s2, d); }
  if ((threadIdx.x & 63) == 0) { red[threadIdx.x >> 6] = s1; red[4 + (threadIdx.x >> 6)] = s2; }
  __syncthreads();
  s1 = red[0] + red[1] + red[2] + red[3];
  s2 = red[4] + red[5] + red[6] + red[7];
  const float mean = s1 * (1.f / 1024.f);
  const float var = s2 * (1.f / 1024.f) - mean * mean;
  const float rs = rsqrtf(var + 1e-5f);
  const float4 g4 = *(const float4*)(lng + e);
  const float4 bb4 = *(const float4*)(lnb + e);
  float o0 = (v[0] - mean) * rs * g4.x + bb4.x;
  float o1 = (v[1] - mean) * rs * g4.y + bb4.y;
  float o2 = (v[2] - mean) * rs * g4.z + bb4.z;
  float o3 = (v[3] - mean) * rs * g4.w + bb4.w;
  *(float4*)(hout + (size_t)s * Hh + e) = make_float4(o0, o1, o2, o3);
  u16x4 ov = {f2bf(o0), f2bf(o1), f2bf(o2), f2bf(o3)};
  *(u16x4*)(xb + (size_t)s * Hh + e) = ov;
}

// ---------------------------------------------------------------------------
// Generalized LayerNorm: v = inA + inB? + resid? + bias?; out h fp32 + x bf16
// ---------------------------------------------------------------------------
__global__ __launch_bounds__(256) void ln_kernel(
    const float* __restrict__ inA, const float* __restrict__ inB,
    const float* __restrict__ resid, const float* __restrict__ bias,
    const float* __restrict__ g, const float* __restrict__ bta,
    float* __restrict__ hout, u16* __restrict__ xb)
{
  __shared__ float red[8];
  const int row = blockIdx.x;
  const int e = threadIdx.x * 4;
  const float4 a4 = *(const float4*)(inA + (size_t)row * Hh + e);
  float v[4] = {a4.x, a4.y, a4.z, a4.w};
  if (inB) {
    const float4 b4 = *(const float4*)(inB + (size_t)row * Hh + e);
    v[0] += b4.x; v[1] += b4.y; v[2] += b4.z; v[3] += b4.w;
  }
  if (resid) {
    const float4 r4 = *(const float4*)(resid + (size_t)row * Hh + e);
    v[0] += r4.x; v[1] += r4.y; v[2] += r4.z; v[3] += r4.w;
  }
  if (bias) {
    const float4 c4 = *(const float4*)(bias + e);
    v[0] += c4.x; v[1] += c4.y; v[2] += c4.z; v[3] += c4.w;
  }
  float s1 = v[0] + v[1] + v[2] + v[3];
  float s2 = v[0]*v[0] + v[1]*v[1] + v[2]*v[2] + v[3]*v[3];
#pragma unroll
  for (int d = 32; d; d >>= 1) { s1 += __shfl_xor(s1, d); s2 += __shfl_xor(s2, d); }
  if ((threadIdx.x & 63) == 0) { red[threadIdx.x >> 6] = s1; red[4 + (threadIdx.x >> 6)] = s2; }
  __syncthreads();
  s1 = red[0] + red[1] + red[2] + red[3];
  s2 = red[4] + red[5] + red[6] + red[7];
  const float mean = s1 * (1.f / 1024.f);
  const float var = s2 * (1.f / 1024.f) - mean * mean;
  const float rs = rsqrtf(var + 1e-5f);
  const float4 g4 = *(const float4*)(g + e);
  const float4 b4 = *(const float4*)(bta + e);
  float o0 = (v[0] - mean) * rs * g4.x + b4.x;
  float o1 = (v[1] - mean) * rs * g4.y + b4.y;
  float o2 = (v[2] - mean) * rs * g4.z + b4.z;
  float o3 = (v[3] - mean) * rs * g4.w + b4.w;
  *(float4*)(hout + (size_t)row * Hh + e) = make_float4(o0, o1, o2, o3);
  u16x4 ov = {f2bf(o0), f2bf(o1), f2bf(o2), f2bf(o3)};
  *(u16x4*)(xb + (size_t)row * Hh + e) = ov;
}

// W [Kd,Nd] fp32  ->  Wt [Nout,Kd] bf16 (rows >= Nd zero-padded)
__global__ __launch_bounds__(256) void transpose_w(
    const float* __restrict__ W, u16* __restrict__ Wt, int Kd, int Nd, int Nout)
{
  __shared__ float tile[32][33];
  const int k0 = blockIdx.x * 32, n0 = blockIdx.y * 32;
  const int tx = threadIdx.x & 31, ty = threadIdx.x >> 5;
#pragma unroll
  for (int rr = 0; rr < 4; ++rr) {
    const int kk = ty + rr * 8;
    const int n = n0 + tx;
    tile[kk][tx] = (n < Nd) ? W[(size_t)(k0 + kk) * Nd + n] : 0.f;
  }
  __syncthreads();
#pragma unroll
  for (int rr = 0; rr < 4; ++rr) {
    Wt[(size_t)(n0 + ty + rr * 8) * Kd + k0 + tx] = f2bf(tile[tx][ty + rr * 8]);
  }
}

// ---------------------------------------------------------------------------
// Per-layer fused weight transpose (fallback path): 6 matrices, one launch.
// ---------------------------------------------------------------------------
__global__ __launch_bounds__(256) void transpose_all(
    const float* __restrict__ Wq, const float* __restrict__ Wk,
    const float* __restrict__ Wv, const float* __restrict__ Wp,
    const float* __restrict__ W1, const float* __restrict__ W2,
    u16* __restrict__ W3T, u16* __restrict__ WpT,
    u16* __restrict__ W1T, u16* __restrict__ W2T)
{
  __shared__ float tile[32][33];
  const int t = blockIdx.x;
  const float* src;
  u16* dst;
  int Kd, Nd, ti;
  if (t < 4096) {
    const int which = t >> 10;
    ti = t & 1023;
    Kd = 1024; Nd = 1024;
    src = (which == 0) ? Wq : (which == 1) ? Wk : (which == 2) ? Wv : Wp;
    dst = (which == 3) ? WpT : (W3T + (size_t)which * 1024 * 1024);
  } else if (t < 8192) {
    ti = t - 4096; Kd = 1024; Nd = 4096; src = W1; dst = W1T;
  } else {
    ti = t - 8192; Kd = 4096; Nd = 1024; src = W2; dst = W2T;
  }
  const int tilesK = Kd >> 5;
  const int k0 = (ti % tilesK) * 32, n0 = (ti / tilesK) * 32;
  const int tx = threadIdx.x & 31, ty = threadIdx.x >> 5;
#pragma unroll
  for (int rr = 0; rr < 4; ++rr) {
    const int kk = ty + rr * 8;
    tile[kk][tx] = src[(size_t)(k0 + kk) * Nd + n0 + tx];
  }
  __syncthreads();
#pragma unroll
  for (int rr = 0; rr < 4; ++rr) {
    dst[(size_t)(n0 + ty + rr * 8) * Kd + k0 + tx] = f2bf(tile[tx][ty + rr * 8]);
  }
}

// ---------------------------------------------------------------------------
// ALL layers' weight transposes in ONE launch (R17): 73728 blocks =
// 6 layers x 12288 tiles. Dst buffers are per-layer (fixed strides).
// ---------------------------------------------------------------------------
__global__ __launch_bounds__(256) void transpose_layers(
    const float* __restrict__ Wq, const float* __restrict__ Wk,
    const float* __restrict__ Wv, const float* __restrict__ Wp,
    const float* __restrict__ W1, const float* __restrict__ W2,
    u16* __restrict__ W3T, u16* __restrict__ WpT,
    u16* __restrict__ W1T, u16* __restrict__ W2T)
{
  __shared__ float tile[32][33];
  int t = blockIdx.x;
  const int layer = t / 12288;
  t -= layer * 12288;
  const size_t oH = (size_t)layer * 1024 * 1024;      // HxH src offset
  const size_t oF = (size_t)layer * 1024 * 4096;      // HxFF / FFxH src offset
  const float* src;
  u16* dst;
  int Kd, Nd, ti;
  if (t < 4096) {
    const int which = t >> 10;
    ti = t & 1023;
    Kd = 1024; Nd = 1024;
    src = ((which == 0) ? Wq : (which == 1) ? Wk : (which == 2) ? Wv : Wp) + oH;
    dst = (which == 3) ? (WpT + oH)
                       : (W3T + (size_t)layer * 3 * 1024 * 1024 + (size_t)which * 1024 * 1024);
  } else if (t < 8192) {
    ti = t - 4096; Kd = 1024; Nd = 4096; src = W1 + oF; dst = W1T + oF;
  } else {
    ti = t - 8192; Kd = 4096; Nd = 1024; src = W2 + oF; dst = W2T + oF;
  }
  const int tilesK = Kd >> 5;
  const int k0 = (ti % tilesK) * 32, n0 = (ti / tilesK) * 32;
  const int tx = threadIdx.x & 31, ty = threadIdx.x >> 5;
#pragma unroll
  for (int rr = 0; rr < 4; ++rr) {
    const int kk = ty + rr * 8;
    tile[kk][tx] = src[(size_t)(k0 + kk) * Nd + n0 + tx];
  }
  __syncthreads();
#pragma unroll
  for (int rr = 0; rr < 4; ++rr) {
    dst[(size_t)(n0 + ty + rr * 8) * Kd + k0 + tx] = f2bf(tile[tx][ty + rr * 8]);
  }
}

// v slice of fused qkv bf16 [B*S, 3072] (cols 2048..3071) -> vt [B, NH, D, S]
__global__ __launch_bounds__(256) void transpose_v(
    const u16* __restrict__ v, u16* __restrict__ vt)
{
  __shared__ u16 tile[64][72];
  const int s0 = blockIdx.x * 64, h = blockIdx.y, b = blockIdx.z;
  const int j8 = (threadIdx.x & 7) * 8;
#pragma unroll
  for (int half = 0; half < 2; ++half) {
    const int i = (threadIdx.x >> 3) + half * 32;
    *(u16x8*)&tile[i][j8] =
        *(const u16x8*)&v[(size_t)(b * Ss + s0 + i) * QKVld + 2048 + h * 64 + j8];
  }
  __syncthreads();
#pragma unroll
  for (int half = 0; half < 2; ++half) {
    const int d = (threadIdx.x >> 3) + half * 32;
    u16x8 ov;
#pragma unroll
    for (int ee = 0; ee < 8; ++ee) ov[ee] = tile[j8 + ee][d];
    *(u16x8*)&vt[((size_t)(b * NHd + h) * 64 + d) * Ss + s0 + j8] = ov;
  }
}

// rtg head
__global__ __launch_bounds__(256) void rtg_head(
    const float* __restrict__ h, const float* __restrict__ Wr1,
    const float* __restrict__ br1, float* __restrict__ out)
{
  const int lane = threadIdx.x & 63, w = threadIdx.x >> 6;
  const int row = blockIdx.x * 4 + w;
  const int b = row >> 8, tt = row & 255;
  const float* x = h + (size_t)(b * Ss + 512 + tt) * Hh;
  float s = 0.f;
  for (int e = lane; e < Hh; e += 64) s += x[e] * Wr1[e];
#pragma unroll
  for (int d = 32; d; d >>= 1) s += __shfl_xor(s, d);
  if (lane == 0) out[row] = s + br1[0];
}

// ---------------------------------------------------------------------------
extern "C" void kernel_launch(void* const* d_in, const int* in_sizes, int n_in,
                              void* d_out, int out_size, void* d_ws, size_t ws_size,
                              hipStream_t stream)
{
  (void)in_sizes; (void)n_in; (void)out_size;
  const int*   timesteps = (const int*)d_in[0];
  const int*   states    = (const int*)d_in[1];
  const int*   actions   = (const int*)d_in[2];
  const float* rtg       = (const float*)d_in[3];
  const float* Wt   = (const float*)d_in[4];
  const float* Ws   = (const float*)d_in[5];
  const float* Wa   = (const float*)d_in[6];
  const float* Wr   = (const float*)d_in[7];
  const float* br   = (const float*)d_in[8];
  const float* lng  = (const float*)d_in[9];
  const float* lnb  = (const float*)d_in[10];
  const float* Wq   = (const float*)d_in[11];
  const float* bq   = (const float*)d_in[12];
  const float* Wk   = (const float*)d_in[13];
  const float* bk   = (const float*)d_in[14];
  const float* Wv   = (const float*)d_in[15];
  const float* bv   = (const float*)d_in[16];
  const float* Wp   = (const float*)d_in[17];
  const float* bp   = (const float*)d_in[18];
  const float* W1   = (const float*)d_in[19];
  const float* b1   = (const float*)d_in[20];
  const float* W2   = (const float*)d_in[21];
  const float* b2   = (const float*)d_in[22];
  const float* ln1g = (const float*)d_in[23];
  const float* ln1b = (const float*)d_in[24];
  const float* ln2g = (const float*)d_in[25];
  const float* ln2b = (const float*)d_in[26];
  const float* Wrtg = (const float*)d_in[27];
  const float* brtg = (const float*)d_in[28];
  const float* Wst  = (const float*)d_in[29];
  const float* bst  = (const float*)d_in[30];
  const float* Wac  = (const float*)d_in[31];
  const float* bac  = (const float*)d_in[32];

  char* wp = (char*)d_ws;
  auto alloc = [&](size_t bytes) { void* p = wp; wp += (bytes + 511) & ~(size_t)511; return p; };
  float* hbuf = (float*)alloc((size_t)BSr * Hh * 4);
  float* p0   = (float*)alloc((size_t)BSr * Hh * 4);
  float* p1   = (float*)alloc((size_t)BSr * Hh * 4);
  u16* xb   = (u16*)alloc((size_t)BSr * Hh * 2);
  u16* qkvb = (u16*)alloc((size_t)BSr * QKVld * 2);
  u16* vtb  = (u16*)alloc((size_t)BSr * Hh * 2);
  u16* ob   = (u16*)alloc((size_t)BSr * Hh * 2);
  u16* ub   = (u16*)alloc((size_t)BSr * FFd * 2);
  u16* WstT = (u16*)alloc((size_t)Hh * Hh * 2);
  u16* WacT = (u16*)alloc((size_t)128 * Hh * 2);

  // weight-transpose buffers: all-layer (preferred) or per-layer (fallback)
  const size_t used = (size_t)(wp - (char*)d_ws);
  const size_t perLayerBytes =
      ((size_t)3 * Hh * Hh + (size_t)Hh * Hh + (size_t)FFd * Hh + (size_t)Hh * FFd) * 2;
  const bool pre = (used + 6 * perLayerBytes + 4096) <= ws_size;
  const int nset = pre ? 6 : 1;
  u16* W3T = (u16*)alloc((size_t)nset * 3 * Hh * Hh * 2);
  u16* WpT = (u16*)alloc((size_t)nset * Hh * Hh * 2);
  u16* W1T = (u16*)alloc((size_t)nset * FFd * Hh * 2);
  u16* W2T = (u16*)alloc((size_t)nset * Hh * FFd * 2);
  const size_t s3 = pre ? (size_t)3 * Hh * Hh : 0;
  const size_t sp = pre ? (size_t)Hh * Hh : 0;
  const size_t s1 = pre ? (size_t)FFd * Hh : 0;
  const size_t s2 = pre ? (size_t)Hh * FFd : 0;

  float* out_state = (float*)d_out;
  float* out_act   = out_state + (size_t)2048 * 1024;
  float* out_rtg   = out_act + (size_t)2048 * 64;

  const size_t PSZ = (size_t)BSr * Hh;

  transpose_w<<<dim3(32, 32, 1), 256, 0, stream>>>(Wst, WstT, 1024, 1024, 1024);
  transpose_w<<<dim3(32, 4, 1), 256, 0, stream>>>(Wac, WacT, 1024, 64, 128);
  if (pre) {
    transpose_layers<<<73728, 256, 0, stream>>>(Wq, Wk, Wv, Wp, W1, W2,
                                                W3T, WpT, W1T, W2T);
  }
  embed_ln<<<BSr, 256, 0, stream>>>(timesteps, states, actions, rtg, Wt, Ws, Wa, Wr,
                                    br, lng, lnb, hbuf, xb);

  for (int l = 0; l < Ll; ++l) {
    if (!pre) {
      transpose_all<<<12288, 256, 0, stream>>>(
          Wq + (size_t)l * Hh * Hh, Wk + (size_t)l * Hh * Hh,
          Wv + (size_t)l * Hh * Hh, Wp + (size_t)l * Hh * Hh,
          W1 + (size_t)l * Hh * FFd, W2 + (size_t)l * FFd * Hh,
          W3T, WpT, W1T, W2T);
    }
    u16* lW3T = W3T + (size_t)l * s3;
    u16* lWpT = WpT + (size_t)l * sp;
    u16* lW1T = W1T + (size_t)l * s1;
    u16* lW2T = W2T + (size_t)l * s2;

    // fused QKV: [6144,1024] x [1024,3072] -> qkvb bf16
    gemm_db<<<dim3(24, 48, 1), 256, 0, stream>>>(
        xb, lW3T, bq + l * Hh, bk + l * Hh, bv + l * Hh, nullptr, qkvb,
        Hh, Hh, QKVld, 0, 0);
    transpose_v<<<dim3(12, 16, 8), 256, 0, stream>>>(qkvb, vtb);
    attn_flash<<<dim3(12, 16, 8), 256, 0, stream>>>(qkvb, vtb, ob);
    // attn out projection, split-K=2 -> partials p0,p1 (bias/resid folded in LN)
    gemm_db<<<dim3(8, 48, 2), 256, 0, stream>>>(
        ob, lWpT, nullptr, nullptr, nullptr, p0, nullptr,
        Hh, 512, Hh, 0, PSZ);
    ln_kernel<<<BSr, 256, 0, stream>>>(p0, p1, hbuf, bp + l * Hh,
                                       ln1g + l * Hh, ln1b + l * Hh, hbuf, xb);
    // FFN1: [6144,1024] x [1024,4096], GELU -> ub bf16
    gemm_db<<<dim3(32, 48, 1), 256, 0, stream>>>(
        xb, lW1T, b1 + l * FFd, nullptr, nullptr, nullptr, ub,
        Hh, Hh, FFd, 1, 0);
    // FFN2: [6144,4096] x [4096,1024], split-K=2 -> p0,p1
    gemm_db<<<dim3(8, 48, 2), 256, 0, stream>>>(
        ub, lW2T, nullptr, nullptr, nullptr, p0, nullptr,
        FFd, 2048, Hh, 0, PSZ);
    ln_kernel<<<BSr, 256, 0, stream>>>(p0, p1, hbuf, b2 + l * Hh,
                                       ln2g + l * Hh, ln2b + l * Hh, hbuf, xb);
  }

  gemm_bf16<<<dim3(8, 16), 256, 0, stream>>>(xb, WstT, bst, out_state,
                                             2048, 1024, 1024, 1024, 1024, 1, 512);
  gemm_bf16<<<dim3(1, 16), 256, 0, stream>>>(xb, WacT, bac, out_act,
                                             2048, 128, 1024, 64, 64, 1, 256);
  rtg_head<<<512, 256, 0, stream>>>(hbuf, Wrtg, brtg, out_rtg);
}

// Round 18
// 2118.047 us; speedup vs baseline: 1.0303x; 1.0303x over previous
//
#include <hip/hip_runtime.h>
#include <hip/hip_bf16.h>

#define DI __device__ __forceinline__

typedef unsigned short u16;
typedef __bf16 bf16x8 __attribute__((ext_vector_type(8)));
typedef unsigned short u16x8 __attribute__((ext_vector_type(8)));
typedef unsigned short u16x4 __attribute__((ext_vector_type(4)));
typedef float f32x4 __attribute__((ext_vector_type(4)));

static constexpr int Bb = 8, Tt = 256, Hh = 1024, Ll = 6, NHd = 16, Dh = 64;
static constexpr int Ss = 3 * Tt;      // 768 tokens
static constexpr int FFd = 4096;
static constexpr int BSr = Bb * Ss;    // 6144 rows
static constexpr int QKVld = 3072;     // fused qkv row stride

DI u16 f2bf(float f) {
  unsigned u = __builtin_bit_cast(unsigned, f);
  u += 0x7fffu + ((u >> 16) & 1u);
  return (u16)(u >> 16);
}

// tanh-form GELU (max |diff| vs erf-GELU ~3e-3, well under 7e-2 threshold)
DI float gelu_f(float x) {
  const float s = 1.5957691216f * x + 0.0713564814f * x * x * x;
  return x / (1.f + __expf(-s));
}

DI void gload_lds16(const u16* g, u16* l) {
  __builtin_amdgcn_global_load_lds((__attribute__((address_space(1))) void*)(g),
                                   (__attribute__((address_space(3))) void*)(l), 16, 0, 0);
}
DI bf16x8 ldl8(const u16* p) { return __builtin_bit_cast(bf16x8, *(const u16x8*)p); }
DI bf16x8 ldg8(const u16* p) { return __builtin_bit_cast(bf16x8, *(const u16x8*)p); }

DI void barRaw() {
  asm volatile("" ::: "memory");
  __builtin_amdgcn_s_barrier();
  asm volatile("" ::: "memory");
}

// ---------------------------------------------------------------------------
// GEMM: 128x128 tile, BK=64, 4 waves, double-buffered LDS (64 KiB, 2/CU).
// K-loop unrolled x2 with static buffer bases (R15); coalesced LDS-staged
// epilogue (R12, C-tile stride 130 u16 -> conflict-free column reads);
// 2D-patch XCD swizzle (R13); tanh-GELU (R15).
// NEW (R18): for the QKV GEMM, V-tiles (bn>=16) are written TRANSPOSED
// directly to vt [B,NH,D,S] from the LDS C-tile (replaces transpose_v;
// qkvb's V columns are written by nothing and read by nothing).
// Optional split-K via blockIdx.z writing fp32 partials at outf + z*psz.
// ---------------------------------------------------------------------------
__global__ __launch_bounds__(256, 2) void gemm_db(
    const u16* __restrict__ A, const u16* __restrict__ Bt,
    const float* __restrict__ bias, const float* __restrict__ bias2,
    const float* __restrict__ bias3,
    float* __restrict__ outf, u16* __restrict__ outb, u16* __restrict__ vt,
    int Kstride, int Ksub, int ldc, int act, size_t psz)
{
  __shared__ u16 SM[32768];   // 64 KiB: A0@0, A1@8192, B0@16384, B1@24576
  const int lane = threadIdx.x & 63, w = threadIdx.x >> 6;
  const int wr = w >> 1, wc = w & 1;
  const int l15 = lane & 15, l4 = lane >> 4;

  // bijective XCD swizzle (m204) + 2D patch mapping (CG=8 cols, bn fastest)
  const int gx = gridDim.x, gy = gridDim.y, nwg = gx * gy;
  int f = blockIdx.y * gx + blockIdx.x;
  { int q = nwg >> 3, rr = nwg & 7, x = f & 7, idx = f >> 3;
    f = (x < rr ? x * (q + 1) : rr * (q + 1) + (x - rr) * q) + idx; }
  const int r2 = f % (gy * 8), cg = f / (gy * 8);
  const int bm = r2 >> 3, bn = cg * 8 + (r2 & 7);
  const int koff = blockIdx.z * Ksub;
  const int NT = Ksub >> 6;   // even for all uses (16 / 32 / 8)

  const int srow = lane >> 3;
  const int schunk = ((lane & 7) ^ srow) << 3;
  unsigned aoff[4], boff[4];
#pragma unroll
  for (int i = 0; i < 4; ++i) {
    const int r = w * 32 + i * 8 + srow;
    aoff[i] = (unsigned)(bm * 128 + r) * (unsigned)Kstride + koff + schunk;
    boff[i] = (unsigned)(bn * 128 + r) * (unsigned)Kstride + koff + schunk;
  }

  auto stage = [&](int bsel, int kt) {
#pragma unroll
    for (int i = 0; i < 4; ++i)
      gload_lds16(A + aoff[i] + kt * 64, &SM[bsel * 8192 + (w * 32 + i * 8) * 64]);
#pragma unroll
    for (int i = 0; i < 4; ++i)
      gload_lds16(Bt + boff[i] + kt * 64, &SM[16384 + bsel * 8192 + (w * 32 + i * 8) * 64]);
  };

  f32x4 acc[4][4] = {};
  const int r7 = l15 & 7;

  auto body = [&](int CB, int tn, bool more) {
    if (more) stage(CB ^ 1, tn);
    bf16x8 af[4][2], bf[4][2];
#pragma unroll
    for (int m = 0; m < 4; ++m) {
#pragma unroll
      for (int kk = 0; kk < 2; ++kk) {
        const int slot = (((kk * 4 + l4) ^ r7) << 3);
        af[m][kk] = ldl8(&SM[CB * 8192 + (wr * 64 + m * 16 + l15) * 64 + slot]);
        bf[m][kk] = ldl8(&SM[16384 + CB * 8192 + (wc * 64 + m * 16 + l15) * 64 + slot]);
      }
    }
    __builtin_amdgcn_s_setprio(1);
#pragma unroll
    for (int kk = 0; kk < 2; ++kk)
#pragma unroll
      for (int m = 0; m < 4; ++m)
#pragma unroll
        for (int n = 0; n < 4; ++n)
          acc[m][n] = __builtin_amdgcn_mfma_f32_16x16x32_bf16(af[m][kk], bf[n][kk], acc[m][n], 0, 0, 0);
    __builtin_amdgcn_s_setprio(0);
    if (more) asm volatile("s_waitcnt vmcnt(0)" ::: "memory");  // aged drain
    barRaw();
  };

  stage(0, 0);
  asm volatile("s_waitcnt vmcnt(0)" ::: "memory");
  barRaw();

  for (int t = 0; t < NT; t += 2) {
    body(0, t + 1, t + 1 < NT);
    body(1, t + 2, t + 2 < NT);
  }

  // ---- coalesced epilogue via LDS staging (C-tile stride 130 u16) ----
  if (outb) {
#pragma unroll
    for (int n = 0; n < 4; ++n) {
      const int col = wc * 64 + n * 16 + l15;
      const int gcol = bn * 128 + col;
      float bval = 0.f;
      if (bias) {
        const float* bp_ = bias;
        int idx = gcol;
        if (bias2 && gcol >= 1024) { bp_ = (gcol >= 2048) ? bias3 : bias2; idx = gcol & 1023; }
        bval = bp_[idx];
      }
#pragma unroll
      for (int m = 0; m < 4; ++m) {
#pragma unroll
        for (int r = 0; r < 4; ++r) {
          const int lrow = wr * 64 + m * 16 + l4 * 4 + r;
          float x = acc[m][n][r] + bval;
          if (act) x = gelu_f(x);
          SM[lrow * 130 + col] = f2bf(x);
        }
      }
    }
    barRaw();
    if (vt && bn >= 16) {
      // V tile: write transposed into vt[B,NH,D,S].
      // rows bm*128.. are tokens of batch b=bm/6 at s0=(bm%6)*128;
      // cols are channels (bn-16)*128 + c -> head h=(bn-16)*2+(c>>6), d=c&63.
      const int bb = bm / 6, s0 = (bm % 6) * 128;
      const int c = threadIdx.x & 127, sh = threadIdx.x >> 7;
      const int h2 = (bn - 16) * 2 + (c >> 6), d = c & 63;
      u16* dst = vt + ((size_t)(bb * NHd + h2) * Dh + d) * Ss + s0 + sh * 64;
#pragma unroll
      for (int jv = 0; jv < 8; ++jv) {
        u16x8 v8;
#pragma unroll
        for (int e = 0; e < 8; ++e)
          v8[e] = SM[(sh * 64 + jv * 8 + e) * 130 + c];
        *(u16x8*)&dst[jv * 8] = v8;
      }
    } else {
#pragma unroll 4
      for (int rr2 = 0; rr2 < 32; ++rr2) {
        const int row = rr2 * 4 + w;
        *(unsigned*)&outb[(size_t)(bm * 128 + row) * ldc + bn * 128 + lane * 2] =
            *(const unsigned*)&SM[row * 130 + lane * 2];
      }
    }
  } else if (outf) {
    float* Cf = (float*)SM;
#pragma unroll
    for (int half = 0; half < 2; ++half) {
      barRaw();
      if (wr == half) {
#pragma unroll
        for (int n = 0; n < 4; ++n) {
          const int col = wc * 64 + n * 16 + l15;
          const int gcol = bn * 128 + col;
          float bval = 0.f;
          if (bias) {
            const float* bp_ = bias;
            int idx = gcol;
            if (bias2 && gcol >= 1024) { bp_ = (gcol >= 2048) ? bias3 : bias2; idx = gcol & 1023; }
            bval = bp_[idx];
          }
#pragma unroll
          for (int m = 0; m < 4; ++m) {
#pragma unroll
            for (int r = 0; r < 4; ++r) {
              float x = acc[m][n][r] + bval;
              if (act) x = gelu_f(x);
              Cf[(m * 16 + l4 * 4 + r) * 128 + col] = x;
            }
          }
        }
      }
      barRaw();
#pragma unroll 4
      for (int rr2 = 0; rr2 < 16; ++rr2) {
        const int row = rr2 * 4 + w;
        *(float2*)&outf[blockIdx.z * psz +
                        (size_t)(bm * 128 + half * 64 + row) * ldc + bn * 128 + lane * 2] =
            *(const float2*)&Cf[row * 128 + lane * 2];
      }
    }
  }
}

// ---------------------------------------------------------------------------
// Small GEMM (heads): 128x128 tile, BK=64, 4 waves, 16x16 MFMA.
// ---------------------------------------------------------------------------
__global__ __launch_bounds__(256, 2) void gemm_bf16(
    const u16* __restrict__ A, const u16* __restrict__ Bt,
    const float* __restrict__ bias, float* __restrict__ outf,
    int M, int N, int K, int ldc, int Nstore, int rowmode, int rowoff)
{
  __shared__ u16 As[128 * 64];
  __shared__ u16 Bs[128 * 64];
  const int tid = threadIdx.x;
  const int lane = tid & 63;
  const int w = tid >> 6;
  const int wr = w >> 1, wc = w & 1;
  const int bn = blockIdx.x, bm = blockIdx.y;
  const int l3 = lane >> 3, l7 = lane & 7, l15 = lane & 15, l4 = lane >> 4;

  f32x4 acc[4][4] = {};

  const int schunk = (l7 ^ l3) << 3;
  size_t aoff[4], boff[4];
#pragma unroll
  for (int i = 0; i < 4; ++i) {
    int r = bm * 128 + w * 32 + i * 8 + l3;
    int ar = rowmode ? ((r >> 8) * Ss + rowoff + (r & 255)) : r;
    aoff[i] = (size_t)ar * K + schunk;
    boff[i] = (size_t)(bn * 128 + w * 32 + i * 8 + l3) * K + schunk;
  }

  for (int kt = 0; kt < K; kt += 64) {
    __syncthreads();
#pragma unroll
    for (int i = 0; i < 4; ++i) {
      gload_lds16(A + aoff[i] + kt, &As[(w * 32 + i * 8) * 64]);
      gload_lds16(Bt + boff[i] + kt, &Bs[(w * 32 + i * 8) * 64]);
    }
    __syncthreads();

    bf16x8 af[4][2], bf[4][2];
#pragma unroll
    for (int m = 0; m < 4; ++m) {
#pragma unroll
      for (int kk = 0; kk < 2; ++kk) {
        const int slot = ((kk * 4 + l4) ^ l7) << 3;
        af[m][kk] = ldl8(&As[(wr * 64 + m * 16 + l15) * 64 + slot]);
        bf[m][kk] = ldl8(&Bs[(wc * 64 + m * 16 + l15) * 64 + slot]);
      }
    }
#pragma unroll
    for (int m = 0; m < 4; ++m)
#pragma unroll
      for (int n = 0; n < 4; ++n)
#pragma unroll
        for (int kk = 0; kk < 2; ++kk)
          acc[m][n] = __builtin_amdgcn_mfma_f32_16x16x32_bf16(af[m][kk], bf[n][kk], acc[m][n], 0, 0, 0);
  }

#pragma unroll
  for (int n = 0; n < 4; ++n) {
    const int col = bn * 128 + wc * 64 + n * 16 + l15;
    const bool cok = col < Nstore;
    const float bv = (cok && bias) ? bias[col] : 0.f;
#pragma unroll
    for (int m = 0; m < 4; ++m) {
#pragma unroll
      for (int r = 0; r < 4; ++r) {
        const int row = bm * 128 + wr * 64 + m * 16 + l4 * 4 + r;
        if (cok) outf[(size_t)row * ldc + col] = acc[m][n][r] + bv;
      }
    }
  }
}

// ---------------------------------------------------------------------------
// Flash attention (unchanged)
// ---------------------------------------------------------------------------
__global__ __launch_bounds__(256, 3) void attn_flash(
    const u16* __restrict__ qkv, const u16* __restrict__ vt, u16* __restrict__ o)
{
  __shared__ u16 Kl[2][64 * 64];
  __shared__ u16 Vl[2][64 * 64];
  __shared__ u16 Pl[4][16 * 64];
  const int qt = blockIdx.x, h = blockIdx.y, b = blockIdx.z;
  const int lane = threadIdx.x & 63, w = threadIdx.x >> 6;
  const int l15 = lane & 15, l4 = lane >> 4;

  const size_t qoff = (size_t)(b * Ss + qt * 64 + w * 16 + l15) * QKVld + h * Dh + l4 * 8;
  const bf16x8 aq0 = ldg8(qkv + qoff), aq1 = ldg8(qkv + qoff + 32);

  const u16* kg = qkv + (size_t)b * Ss * QKVld + 1024 + h * Dh;
  const u16* vg = vt + (size_t)(b * NHd + h) * Dh * Ss;

  int srow[2], scs[2];
#pragma unroll
  for (int i = 0; i < 2; ++i) {
    srow[i] = (w * 2 + i) * 8 + (lane >> 3);
    scs[i] = ((lane & 7) ^ (srow[i] & 7)) * 8;
  }

  float m[4] = {-1e30f, -1e30f, -1e30f, -1e30f};
  float lsum[4] = {0.f, 0.f, 0.f, 0.f};
  f32x4 oa[4] = {};

  auto stage = [&](int bsel, int kb) {
#pragma unroll
    for (int i = 0; i < 2; ++i) {
      gload_lds16(kg + (size_t)(kb * 64 + srow[i]) * QKVld + scs[i], &Kl[bsel][(w * 2 + i) * 8 * 64]);
      gload_lds16(vg + (size_t)srow[i] * Ss + kb * 64 + scs[i], &Vl[bsel][(w * 2 + i) * 8 * 64]);
    }
  };

  stage(0, 0);
  __syncthreads();
  int buf = 0;
  for (int kb = 0; kb <= qt; ++kb) {
    if (kb < qt) stage(buf ^ 1, kb + 1);

    f32x4 sc[4];
    __builtin_amdgcn_s_setprio(1);
#pragma unroll
    for (int fj = 0; fj < 4; ++fj) {
      const u16* kp = &Kl[buf][(fj * 16 + l15) * 64];
      const int r7 = l15 & 7;
      bf16x8 kf0 = ldl8(kp + ((l4 ^ r7) << 3));
      bf16x8 kf1 = ldl8(kp + (((4 + l4) ^ r7) << 3));
      f32x4 zz = {};
      zz = __builtin_amdgcn_mfma_f32_16x16x32_bf16(aq0, kf0, zz, 0, 0, 0);
      sc[fj] = __builtin_amdgcn_mfma_f32_16x16x32_bf16(aq1, kf1, zz, 0, 0, 0);
    }
    __builtin_amdgcn_s_setprio(0);

    float pm[4] = {-1e30f, -1e30f, -1e30f, -1e30f};
    const bool diag = (kb == qt);
#pragma unroll
    for (int fj = 0; fj < 4; ++fj)
#pragma unroll
      for (int r = 0; r < 4; ++r) {
        float s = sc[fj][r] * 0.125f;
        if (diag && (fj * 16 + l15) > (w * 16 + l4 * 4 + r)) s = -1e30f;
        sc[fj][r] = s;
        pm[r] = fmaxf(pm[r], s);
      }
#pragma unroll
    for (int d = 1; d < 16; d <<= 1)
#pragma unroll
      for (int r = 0; r < 4; ++r) pm[r] = fmaxf(pm[r], __shfl_xor(pm[r], d));

    float al[4], ps[4];
#pragma unroll
    for (int r = 0; r < 4; ++r) {
      float mn = fmaxf(m[r], pm[r]);
      al[r] = __expf(m[r] - mn);
      m[r] = mn;
      ps[r] = 0.f;
    }
#pragma unroll
    for (int fj = 0; fj < 4; ++fj)
#pragma unroll
      for (int r = 0; r < 4; ++r) {
        float p = __expf(sc[fj][r] - m[r]);
        sc[fj][r] = p;
        ps[r] += p;
      }
#pragma unroll
    for (int d = 1; d < 16; d <<= 1)
#pragma unroll
      for (int r = 0; r < 4; ++r) ps[r] += __shfl_xor(ps[r], d);
#pragma unroll
    for (int r = 0; r < 4; ++r) lsum[r] = lsum[r] * al[r] + ps[r];
#pragma unroll
    for (int fn = 0; fn < 4; ++fn)
#pragma unroll
      for (int r = 0; r < 4; ++r) oa[fn][r] *= al[r];

#pragma unroll
    for (int fj = 0; fj < 4; ++fj)
#pragma unroll
      for (int r = 0; r < 4; ++r) {
        const int key = fj * 16 + l15, qloc = l4 * 4 + r;
        Pl[w][qloc * 64 + (((key >> 3) ^ (qloc & 7)) << 3) + (key & 7)] = f2bf(sc[fj][r]);
      }

    const int q7 = l15 & 7;
    bf16x8 pa0 = ldl8(&Pl[w][l15 * 64 + ((l4 ^ q7) << 3)]);
    bf16x8 pa1 = ldl8(&Pl[w][l15 * 64 + (((4 + l4) ^ q7) << 3)]);
    __builtin_amdgcn_s_setprio(1);
#pragma unroll
    for (int fn = 0; fn < 4; ++fn) {
      const u16* vp = &Vl[buf][(fn * 16 + l15) * 64];
      bf16x8 vf0 = ldl8(vp + ((l4 ^ q7) << 3));
      bf16x8 vf1 = ldl8(vp + (((4 + l4) ^ q7) << 3));
      oa[fn] = __builtin_amdgcn_mfma_f32_16x16x32_bf16(pa0, vf0, oa[fn], 0, 0, 0);
      oa[fn] = __builtin_amdgcn_mfma_f32_16x16x32_bf16(pa1, vf1, oa[fn], 0, 0, 0);
    }
    __builtin_amdgcn_s_setprio(0);
    __syncthreads();
    buf ^= 1;
  }

#pragma unroll
  for (int fn = 0; fn < 4; ++fn)
#pragma unroll
    for (int r = 0; r < 4; ++r) {
      const int row = b * Ss + qt * 64 + w * 16 + l4 * 4 + r;
      o[(size_t)row * Hh + h * Dh + fn * 16 + l15] = f2bf(oa[fn][r] / lsum[r]);
    }
}

// ---------------------------------------------------------------------------
// Embedding + interleave + LayerNorm -> h (fp32) and x (bf16)
// ---------------------------------------------------------------------------
__global__ __launch_bounds__(256) void embed_ln(
    const int* __restrict__ timesteps, const int* __restrict__ states,
    const int* __restrict__ actions, const float* __restrict__ rtg,
    const float* __restrict__ Wt, const float* __restrict__ Ws,
    const float* __restrict__ Wa, const float* __restrict__ Wr,
    const float* __restrict__ br, const float* __restrict__ lng,
    const float* __restrict__ lnb, float* __restrict__ hout, u16* __restrict__ xb)
{
  __shared__ float red[8];
  const int s = blockIdx.x;
  const int b = s / Ss, sl = s % Ss;
  const int tt = sl / 3, kind = sl % 3;
  const int bt = b * Tt + tt;
  const int e = threadIdx.x * 4;

  const float4 tv = *(const float4*)(Wt + (size_t)timesteps[bt] * Hh + e);
  float v[4];
  if (kind == 0) {
    const float rr = rtg[bt];
    const float4 w4 = *(const float4*)(Wr + e);
    const float4 b4 = *(const float4*)(br + e);
    v[0] = rr * w4.x + b4.x + tv.x; v[1] = rr * w4.y + b4.y + tv.y;
    v[2] = rr * w4.z + b4.z + tv.z; v[3] = rr * w4.w + b4.w + tv.w;
  } else {
    const float* emb = (kind == 1) ? (Ws + (size_t)states[bt] * Hh)
                                   : (Wa + (size_t)actions[bt] * Hh);
    const float4 e4 = *(const float4*)(emb + e);
    v[0] = e4.x + tv.x; v[1] = e4.y + tv.y; v[2] = e4.z + tv.z; v[3] = e4.w + tv.w;
  }
  float s1 = v[0] + v[1] + v[2] + v[3];
  float s2 = v[0]*v[0] + v[1]*v[1] + v[2]*v[2] + v[3]*v[3];
#pragma unroll
  for (int d = 32; d; d >>= 1) { s1 += __shfl_xor(s1, d); s2 += __shfl_xor(s2, d); }
  if ((threadIdx.x & 63) == 0) { red[threadIdx.x >> 6] = s1; red[4 + (threadIdx.x >> 6)] = s2; }
  __syncthreads();
  s1 = red[0] + red[1] + red[2] + red[3];
  s2 = red[4] + red[5] + red[6] + red[7];
  const float mean = s1 * (1.f / 1024.f);
  const float var = s2 * (1.f / 1024.f) - mean * mean;
  const float rs = rsqrtf(var + 1e-5f);
  const float4 g4 = *(const float4*)(lng + e);
  const float4 bb4 = *(const float4*)(lnb + e);
  float o0 = (v[0] - mean) * rs * g4.x + bb4.x;
  float o1 = (v[1] - mean) * rs * g4.y + bb4.y;
  float o2 = (v[2] - mean) * rs * g4.z + bb4.z;
  float o3 = (v[3] - mean) * rs * g4.w + bb4.w;
  *(float4*)(hout + (size_t)s * Hh + e) = make_float4(o0, o1, o2, o3);
  u16x4 ov = {f2bf(o0), f2bf(o1), f2bf(o2), f2bf(o3)};
  *(u16x4*)(xb + (size_t)s * Hh + e) = ov;
}

// ---------------------------------------------------------------------------
// Generalized LayerNorm: v = inA + inB? + resid? + bias?; out h fp32 + x bf16
// ---------------------------------------------------------------------------
__global__ __launch_bounds__(256) void ln_kernel(
    const float* __restrict__ inA, const float* __restrict__ inB,
    const float* __restrict__ resid, const float* __restrict__ bias,
    const float* __restrict__ g, const float* __restrict__ bta,
    float* __restrict__ hout, u16* __restrict__ xb)
{
  __shared__ float red[8];
  const int row = blockIdx.x;
  const int e = threadIdx.x * 4;
  const float4 a4 = *(const float4*)(inA + (size_t)row * Hh + e);
  float v[4] = {a4.x, a4.y, a4.z, a4.w};
  if (inB) {
    const float4 b4 = *(const float4*)(inB + (size_t)row * Hh + e);
    v[0] += b4.x; v[1] += b4.y; v[2] += b4.z; v[3] += b4.w;
  }
  if (resid) {
    const float4 r4 = *(const float4*)(resid + (size_t)row * Hh + e);
    v[0] += r4.x; v[1] += r4.y; v[2] += r4.z; v[3] += r4.w;
  }
  if (bias) {
    const float4 c4 = *(const float4*)(bias + e);
    v[0] += c4.x; v[1] += c4.y; v[2] += c4.z; v[3] += c4.w;
  }
  float s1 = v[0] + v[1] + v[2] + v[3];
  float s2 = v[0]*v[0] + v[1]*v[1] + v[2]*v[2] + v[3]*v[3];
#pragma unroll
  for (int d = 32; d; d >>= 1) { s1 += __shfl_xor(s1, d); s2 += __shfl_xor(s2, d); }
  if ((threadIdx.x & 63) == 0) { red[threadIdx.x >> 6] = s1; red[4 + (threadIdx.x >> 6)] = s2; }
  __syncthreads();
  s1 = red[0] + red[1] + red[2] + red[3];
  s2 = red[4] + red[5] + red[6] + red[7];
  const float mean = s1 * (1.f / 1024.f);
  const float var = s2 * (1.f / 1024.f) - mean * mean;
  const float rs = rsqrtf(var + 1e-5f);
  const float4 g4 = *(const float4*)(g + e);
  const float4 b4 = *(const float4*)(bta + e);
  float o0 = (v[0] - mean) * rs * g4.x + b4.x;
  float o1 = (v[1] - mean) * rs * g4.y + b4.y;
  float o2 = (v[2] - mean) * rs * g4.z + b4.z;
  float o3 = (v[3] - mean) * rs * g4.w + b4.w;
  *(float4*)(hout + (size_t)row * Hh + e) = make_float4(o0, o1, o2, o3);
  u16x4 ov = {f2bf(o0), f2bf(o1), f2bf(o2), f2bf(o3)};
  *(u16x4*)(xb + (size_t)row * Hh + e) = ov;
}

// W [Kd,Nd] fp32  ->  Wt [Nout,Kd] bf16 (rows >= Nd zero-padded)
__global__ __launch_bounds__(256) void transpose_w(
    const float* __restrict__ W, u16* __restrict__ Wt, int Kd, int Nd, int Nout)
{
  __shared__ float tile[32][33];
  const int k0 = blockIdx.x * 32, n0 = blockIdx.y * 32;
  const int tx = threadIdx.x & 31, ty = threadIdx.x >> 5;
#pragma unroll
  for (int rr = 0; rr < 4; ++rr) {
    const int kk = ty + rr * 8;
    const int n = n0 + tx;
    tile[kk][tx] = (n < Nd) ? W[(size_t)(k0 + kk) * Nd + n] : 0.f;
  }
  __syncthreads();
#pragma unroll
  for (int rr = 0; rr < 4; ++rr) {
    Wt[(size_t)(n0 + ty + rr * 8) * Kd + k0 + tx] = f2bf(tile[tx][ty + rr * 8]);
  }
}

// ---------------------------------------------------------------------------
// Fused per-layer weight transpose: all 6 matrices in ONE launch (R16).
// ---------------------------------------------------------------------------
__global__ __launch_bounds__(256) void transpose_all(
    const float* __restrict__ Wq, const float* __restrict__ Wk,
    const float* __restrict__ Wv, const float* __restrict__ Wp,
    const float* __restrict__ W1, const float* __restrict__ W2,
    u16* __restrict__ W3T, u16* __restrict__ WpT,
    u16* __restrict__ W1T, u16* __restrict__ W2T)
{
  __shared__ float tile[32][33];
  const int t = blockIdx.x;
  const float* src;
  u16* dst;
  int Kd, Nd, ti;
  if (t < 4096) {
    const int which = t >> 10;
    ti = t & 1023;
    Kd = 1024; Nd = 1024;
    src = (which == 0) ? Wq : (which == 1) ? Wk : (which == 2) ? Wv : Wp;
    dst = (which == 3) ? WpT : (W3T + (size_t)which * 1024 * 1024);
  } else if (t < 8192) {
    ti = t - 4096; Kd = 1024; Nd = 4096; src = W1; dst = W1T;
  } else {
    ti = t - 8192; Kd = 4096; Nd = 1024; src = W2; dst = W2T;
  }
  const int tilesK = Kd >> 5;
  const int k0 = (ti % tilesK) * 32, n0 = (ti / tilesK) * 32;
  const int tx = threadIdx.x & 31, ty = threadIdx.x >> 5;
#pragma unroll
  for (int rr = 0; rr < 4; ++rr) {
    const int kk = ty + rr * 8;
    tile[kk][tx] = src[(size_t)(k0 + kk) * Nd + n0 + tx];
  }
  __syncthreads();
#pragma unroll
  for (int rr = 0; rr < 4; ++rr) {
    dst[(size_t)(n0 + ty + rr * 8) * Kd + k0 + tx] = f2bf(tile[tx][ty + rr * 8]);
  }
}

// rtg head
__global__ __launch_bounds__(256) void rtg_head(
    const float* __restrict__ h, const float* __restrict__ Wr1,
    const float* __restrict__ br1, float* __restrict__ out)
{
  const int lane = threadIdx.x & 63, w = threadIdx.x >> 6;
  const int row = blockIdx.x * 4 + w;
  const int b = row >> 8, tt = row & 255;
  const float* x = h + (size_t)(b * Ss + 512 + tt) * Hh;
  float s = 0.f;
  for (int e = lane; e < Hh; e += 64) s += x[e] * Wr1[e];
#pragma unroll
  for (int d = 32; d; d >>= 1) s += __shfl_xor(s, d);
  if (lane == 0) out[row] = s + br1[0];
}

// ---------------------------------------------------------------------------
extern "C" void kernel_launch(void* const* d_in, const int* in_sizes, int n_in,
                              void* d_out, int out_size, void* d_ws, size_t ws_size,
                              hipStream_t stream)
{
  (void)in_sizes; (void)n_in; (void)out_size; (void)ws_size;
  const int*   timesteps = (const int*)d_in[0];
  const int*   states    = (const int*)d_in[1];
  const int*   actions   = (const int*)d_in[2];
  const float* rtg       = (const float*)d_in[3];
  const float* Wt   = (const float*)d_in[4];
  const float* Ws   = (const float*)d_in[5];
  const float* Wa   = (const float*)d_in[6];
  const float* Wr   = (const float*)d_in[7];
  const float* br   = (const float*)d_in[8];
  const float* lng  = (const float*)d_in[9];
  const float* lnb  = (const float*)d_in[10];
  const float* Wq   = (const float*)d_in[11];
  const float* bq   = (const float*)d_in[12];
  const float* Wk   = (const float*)d_in[13];
  const float* bk   = (const float*)d_in[14];
  const float* Wv   = (const float*)d_in[15];
  const float* bv   = (const float*)d_in[16];
  const float* Wp   = (const float*)d_in[17];
  const float* bp   = (const float*)d_in[18];
  const float* W1   = (const float*)d_in[19];
  const float* b1   = (const float*)d_in[20];
  const float* W2   = (const float*)d_in[21];
  const float* b2   = (const float*)d_in[22];
  const float* ln1g = (const float*)d_in[23];
  const float* ln1b = (const float*)d_in[24];
  const float* ln2g = (const float*)d_in[25];
  const float* ln2b = (const float*)d_in[26];
  const float* Wrtg = (const float*)d_in[27];
  const float* brtg = (const float*)d_in[28];
  const float* Wst  = (const float*)d_in[29];
  const float* bst  = (const float*)d_in[30];
  const float* Wac  = (const float*)d_in[31];
  const float* bac  = (const float*)d_in[32];

  char* wp = (char*)d_ws;
  auto alloc = [&](size_t bytes) { void* p = wp; wp += (bytes + 511) & ~(size_t)511; return p; };
  float* hbuf = (float*)alloc((size_t)BSr * Hh * 4);
  float* p0   = (float*)alloc((size_t)BSr * Hh * 4);
  float* p1   = (float*)alloc((size_t)BSr * Hh * 4);
  u16* xb   = (u16*)alloc((size_t)BSr * Hh * 2);
  u16* qkvb = (u16*)alloc((size_t)BSr * QKVld * 2);
  u16* vtb  = (u16*)alloc((size_t)BSr * Hh * 2);
  u16* ob   = (u16*)alloc((size_t)BSr * Hh * 2);
  u16* ub   = (u16*)alloc((size_t)BSr * FFd * 2);
  u16* W3T  = (u16*)alloc((size_t)3 * Hh * Hh * 2);
  u16* WpT  = (u16*)alloc((size_t)Hh * Hh * 2);
  u16* W1T  = (u16*)alloc((size_t)FFd * Hh * 2);
  u16* W2T  = (u16*)alloc((size_t)Hh * FFd * 2);
  u16* WstT = (u16*)alloc((size_t)Hh * Hh * 2);
  u16* WacT = (u16*)alloc((size_t)128 * Hh * 2);

  float* out_state = (float*)d_out;
  float* out_act   = out_state + (size_t)2048 * 1024;
  float* out_rtg   = out_act + (size_t)2048 * 64;

  const size_t PSZ = (size_t)BSr * Hh;

  transpose_w<<<dim3(32, 32, 1), 256, 0, stream>>>(Wst, WstT, 1024, 1024, 1024);
  transpose_w<<<dim3(32, 4, 1), 256, 0, stream>>>(Wac, WacT, 1024, 64, 128);
  embed_ln<<<BSr, 256, 0, stream>>>(timesteps, states, actions, rtg, Wt, Ws, Wa, Wr,
                                    br, lng, lnb, hbuf, xb);

  for (int l = 0; l < Ll; ++l) {
    transpose_all<<<12288, 256, 0, stream>>>(
        Wq + (size_t)l * Hh * Hh, Wk + (size_t)l * Hh * Hh,
        Wv + (size_t)l * Hh * Hh, Wp + (size_t)l * Hh * Hh,
        W1 + (size_t)l * Hh * FFd, W2 + (size_t)l * FFd * Hh,
        W3T, WpT, W1T, W2T);

    // fused QKV: [6144,1024] x [1024,3072] -> qkvb (Q,K) + vtb (V transposed)
    gemm_db<<<dim3(24, 48, 1), 256, 0, stream>>>(
        xb, W3T, bq + l * Hh, bk + l * Hh, bv + l * Hh, nullptr, qkvb, vtb,
        Hh, Hh, QKVld, 0, 0);
    attn_flash<<<dim3(12, 16, 8), 256, 0, stream>>>(qkvb, vtb, ob);
    // attn out projection, split-K=2 -> partials p0,p1 (bias/resid folded in LN)
    gemm_db<<<dim3(8, 48, 2), 256, 0, stream>>>(
        ob, WpT, nullptr, nullptr, nullptr, p0, nullptr, nullptr,
        Hh, 512, Hh, 0, PSZ);
    ln_kernel<<<BSr, 256, 0, stream>>>(p0, p1, hbuf, bp + l * Hh,
                                       ln1g + l * Hh, ln1b + l * Hh, hbuf, xb);
    // FFN1: [6144,1024] x [1024,4096], GELU -> ub bf16
    gemm_db<<<dim3(32, 48, 1), 256, 0, stream>>>(
        xb, W1T, b1 + l * FFd, nullptr, nullptr, nullptr, ub, nullptr,
        Hh, Hh, FFd, 1, 0);
    // FFN2: [6144,4096] x [4096,1024], split-K=2 -> p0,p1
    gemm_db<<<dim3(8, 48, 2), 256, 0, stream>>>(
        ub, W2T, nullptr, nullptr, nullptr, p0, nullptr, nullptr,
        FFd, 2048, Hh, 0, PSZ);
    ln_kernel<<<BSr, 256, 0, stream>>>(p0, p1, hbuf, b2 + l * Hh,
                                       ln2g + l * Hh, ln2b + l * Hh, hbuf, xb);
  }

  gemm_bf16<<<dim3(8, 16), 256, 0, stream>>>(xb, WstT, bst, out_state,
                                             2048, 1024, 1024, 1024, 1024, 1, 512);
  gemm_bf16<<<dim3(1, 16), 256, 0, stream>>>(xb, WacT, bac, out_act,
                                             2048, 128, 1024, 64, 64, 1, 256);
  rtg_head<<<512, 256, 0, stream>>>(hbuf, Wrtg, brtg, out_rtg);
}

// Round 19
// 2034.728 us; speedup vs baseline: 1.0725x; 1.0409x over previous
//
#include <hip/hip_runtime.h>
#include <hip/hip_bf16.h>

#define DI __device__ __forceinline__

typedef unsigned short u16;
typedef __bf16 bf16x8 __attribute__((ext_vector_type(8)));
typedef unsigned short u16x8 __attribute__((ext_vector_type(8)));
typedef unsigned short u16x4 __attribute__((ext_vector_type(4)));
typedef float f32x4 __attribute__((ext_vector_type(4)));

static constexpr int Bb = 8, Tt = 256, Hh = 1024, Ll = 6, NHd = 16, Dh = 64;
static constexpr int Ss = 3 * Tt;      // 768 tokens
static constexpr int FFd = 4096;
static constexpr int BSr = Bb * Ss;    // 6144 rows
static constexpr int QKVld = 3072;     // fused qkv row stride

DI u16 f2bf(float f) {
  unsigned u = __builtin_bit_cast(unsigned, f);
  u += 0x7fffu + ((u >> 16) & 1u);
  return (u16)(u >> 16);
}
DI float bf2f(u16 h) { return __builtin_bit_cast(float, (unsigned)h << 16); }

// tanh-form GELU (max |diff| vs erf-GELU ~3e-3, well under 7e-2 threshold)
DI float gelu_f(float x) {
  const float s = 1.5957691216f * x + 0.0713564814f * x * x * x;
  return x / (1.f + __expf(-s));
}

DI void gload_lds16(const u16* g, u16* l) {
  __builtin_amdgcn_global_load_lds((__attribute__((address_space(1))) void*)(g),
                                   (__attribute__((address_space(3))) void*)(l), 16, 0, 0);
}
DI bf16x8 ldl8(const u16* p) { return __builtin_bit_cast(bf16x8, *(const u16x8*)p); }
DI bf16x8 ldg8(const u16* p) { return __builtin_bit_cast(bf16x8, *(const u16x8*)p); }

DI void barRaw() {
  asm volatile("" ::: "memory");
  __builtin_amdgcn_s_barrier();
  asm volatile("" ::: "memory");
}

// ---------------------------------------------------------------------------
// GEMM: 128x128 tile, BK=64, 4 waves, double-buffered LDS (64 KiB, 2/CU).
// K-loop unrolled x2 static bases (R15); coalesced LDS-staged epilogue (R12,
// stride-130 C-tile); 2D-patch XCD swizzle (R13); tanh-GELU (R15); fused
// V-transpose for QKV (R18). NEW (R19): bf16 outb path honors split-K
// (outb + z*psz) so split-K partials are bf16 (halves partial traffic).
// ---------------------------------------------------------------------------
__global__ __launch_bounds__(256, 2) void gemm_db(
    const u16* __restrict__ A, const u16* __restrict__ Bt,
    const float* __restrict__ bias, const float* __restrict__ bias2,
    const float* __restrict__ bias3,
    float* __restrict__ outf, u16* __restrict__ outb, u16* __restrict__ vt,
    int Kstride, int Ksub, int ldc, int act, size_t psz)
{
  __shared__ u16 SM[32768];   // 64 KiB: A0@0, A1@8192, B0@16384, B1@24576
  const int lane = threadIdx.x & 63, w = threadIdx.x >> 6;
  const int wr = w >> 1, wc = w & 1;
  const int l15 = lane & 15, l4 = lane >> 4;

  // bijective XCD swizzle (m204) + 2D patch mapping (CG=8 cols, bn fastest)
  const int gx = gridDim.x, gy = gridDim.y, nwg = gx * gy;
  int f = blockIdx.y * gx + blockIdx.x;
  { int q = nwg >> 3, rr = nwg & 7, x = f & 7, idx = f >> 3;
    f = (x < rr ? x * (q + 1) : rr * (q + 1) + (x - rr) * q) + idx; }
  const int r2 = f % (gy * 8), cg = f / (gy * 8);
  const int bm = r2 >> 3, bn = cg * 8 + (r2 & 7);
  const int koff = blockIdx.z * Ksub;
  const int NT = Ksub >> 6;   // even for all uses (16 / 32 / 8)

  const int srow = lane >> 3;
  const int schunk = ((lane & 7) ^ srow) << 3;
  unsigned aoff[4], boff[4];
#pragma unroll
  for (int i = 0; i < 4; ++i) {
    const int r = w * 32 + i * 8 + srow;
    aoff[i] = (unsigned)(bm * 128 + r) * (unsigned)Kstride + koff + schunk;
    boff[i] = (unsigned)(bn * 128 + r) * (unsigned)Kstride + koff + schunk;
  }

  auto stage = [&](int bsel, int kt) {
#pragma unroll
    for (int i = 0; i < 4; ++i)
      gload_lds16(A + aoff[i] + kt * 64, &SM[bsel * 8192 + (w * 32 + i * 8) * 64]);
#pragma unroll
    for (int i = 0; i < 4; ++i)
      gload_lds16(Bt + boff[i] + kt * 64, &SM[16384 + bsel * 8192 + (w * 32 + i * 8) * 64]);
  };

  f32x4 acc[4][4] = {};
  const int r7 = l15 & 7;

  auto body = [&](int CB, int tn, bool more) {
    if (more) stage(CB ^ 1, tn);
    bf16x8 af[4][2], bf[4][2];
#pragma unroll
    for (int m = 0; m < 4; ++m) {
#pragma unroll
      for (int kk = 0; kk < 2; ++kk) {
        const int slot = (((kk * 4 + l4) ^ r7) << 3);
        af[m][kk] = ldl8(&SM[CB * 8192 + (wr * 64 + m * 16 + l15) * 64 + slot]);
        bf[m][kk] = ldl8(&SM[16384 + CB * 8192 + (wc * 64 + m * 16 + l15) * 64 + slot]);
      }
    }
    __builtin_amdgcn_s_setprio(1);
#pragma unroll
    for (int kk = 0; kk < 2; ++kk)
#pragma unroll
      for (int m = 0; m < 4; ++m)
#pragma unroll
        for (int n = 0; n < 4; ++n)
          acc[m][n] = __builtin_amdgcn_mfma_f32_16x16x32_bf16(af[m][kk], bf[n][kk], acc[m][n], 0, 0, 0);
    __builtin_amdgcn_s_setprio(0);
    if (more) asm volatile("s_waitcnt vmcnt(0)" ::: "memory");  // aged drain
    barRaw();
  };

  stage(0, 0);
  asm volatile("s_waitcnt vmcnt(0)" ::: "memory");
  barRaw();

  for (int t = 0; t < NT; t += 2) {
    body(0, t + 1, t + 1 < NT);
    body(1, t + 2, t + 2 < NT);
  }

  // ---- coalesced epilogue via LDS staging (C-tile stride 130 u16) ----
  if (outb) {
#pragma unroll
    for (int n = 0; n < 4; ++n) {
      const int col = wc * 64 + n * 16 + l15;
      const int gcol = bn * 128 + col;
      float bval = 0.f;
      if (bias) {
        const float* bp_ = bias;
        int idx = gcol;
        if (bias2 && gcol >= 1024) { bp_ = (gcol >= 2048) ? bias3 : bias2; idx = gcol & 1023; }
        bval = bp_[idx];
      }
#pragma unroll
      for (int m = 0; m < 4; ++m) {
#pragma unroll
        for (int r = 0; r < 4; ++r) {
          const int lrow = wr * 64 + m * 16 + l4 * 4 + r;
          float x = acc[m][n][r] + bval;
          if (act) x = gelu_f(x);
          SM[lrow * 130 + col] = f2bf(x);
        }
      }
    }
    barRaw();
    if (vt && bn >= 16) {
      // V tile: write transposed into vt[B,NH,D,S].
      const int bb = bm / 6, s0 = (bm % 6) * 128;
      const int c = threadIdx.x & 127, sh = threadIdx.x >> 7;
      const int h2 = (bn - 16) * 2 + (c >> 6), d = c & 63;
      u16* dst = vt + ((size_t)(bb * NHd + h2) * Dh + d) * Ss + s0 + sh * 64;
#pragma unroll
      for (int jv = 0; jv < 8; ++jv) {
        u16x8 v8;
#pragma unroll
        for (int e = 0; e < 8; ++e)
          v8[e] = SM[(sh * 64 + jv * 8 + e) * 130 + c];
        *(u16x8*)&dst[jv * 8] = v8;
      }
    } else {
      u16* ob2 = outb + blockIdx.z * psz;
#pragma unroll 4
      for (int rr2 = 0; rr2 < 32; ++rr2) {
        const int row = rr2 * 4 + w;
        *(unsigned*)&ob2[(size_t)(bm * 128 + row) * ldc + bn * 128 + lane * 2] =
            *(const unsigned*)&SM[row * 130 + lane * 2];
      }
    }
  } else if (outf) {
    float* Cf = (float*)SM;
#pragma unroll
    for (int half = 0; half < 2; ++half) {
      barRaw();
      if (wr == half) {
#pragma unroll
        for (int n = 0; n < 4; ++n) {
          const int col = wc * 64 + n * 16 + l15;
          const int gcol = bn * 128 + col;
          float bval = 0.f;
          if (bias) {
            const float* bp_ = bias;
            int idx = gcol;
            if (bias2 && gcol >= 1024) { bp_ = (gcol >= 2048) ? bias3 : bias2; idx = gcol & 1023; }
            bval = bp_[idx];
          }
#pragma unroll
          for (int m = 0; m < 4; ++m) {
#pragma unroll
            for (int r = 0; r < 4; ++r) {
              float x = acc[m][n][r] + bval;
              if (act) x = gelu_f(x);
              Cf[(m * 16 + l4 * 4 + r) * 128 + col] = x;
            }
          }
        }
      }
      barRaw();
#pragma unroll 4
      for (int rr2 = 0; rr2 < 16; ++rr2) {
        const int row = rr2 * 4 + w;
        *(float2*)&outf[blockIdx.z * psz +
                        (size_t)(bm * 128 + half * 64 + row) * ldc + bn * 128 + lane * 2] =
            *(const float2*)&Cf[row * 128 + lane * 2];
      }
    }
  }
}

// ---------------------------------------------------------------------------
// Small GEMM (heads): 128x128 tile, BK=64, 4 waves, 16x16 MFMA.
// ---------------------------------------------------------------------------
__global__ __launch_bounds__(256, 2) void gemm_bf16(
    const u16* __restrict__ A, const u16* __restrict__ Bt,
    const float* __restrict__ bias, float* __restrict__ outf,
    int M, int N, int K, int ldc, int Nstore, int rowmode, int rowoff)
{
  __shared__ u16 As[128 * 64];
  __shared__ u16 Bs[128 * 64];
  const int tid = threadIdx.x;
  const int lane = tid & 63;
  const int w = tid >> 6;
  const int wr = w >> 1, wc = w & 1;
  const int bn = blockIdx.x, bm = blockIdx.y;
  const int l3 = lane >> 3, l7 = lane & 7, l15 = lane & 15, l4 = lane >> 4;

  f32x4 acc[4][4] = {};

  const int schunk = (l7 ^ l3) << 3;
  size_t aoff[4], boff[4];
#pragma unroll
  for (int i = 0; i < 4; ++i) {
    int r = bm * 128 + w * 32 + i * 8 + l3;
    int ar = rowmode ? ((r >> 8) * Ss + rowoff + (r & 255)) : r;
    aoff[i] = (size_t)ar * K + schunk;
    boff[i] = (size_t)(bn * 128 + w * 32 + i * 8 + l3) * K + schunk;
  }

  for (int kt = 0; kt < K; kt += 64) {
    __syncthreads();
#pragma unroll
    for (int i = 0; i < 4; ++i) {
      gload_lds16(A + aoff[i] + kt, &As[(w * 32 + i * 8) * 64]);
      gload_lds16(Bt + boff[i] + kt, &Bs[(w * 32 + i * 8) * 64]);
    }
    __syncthreads();

    bf16x8 af[4][2], bf[4][2];
#pragma unroll
    for (int m = 0; m < 4; ++m) {
#pragma unroll
      for (int kk = 0; kk < 2; ++kk) {
        const int slot = ((kk * 4 + l4) ^ l7) << 3;
        af[m][kk] = ldl8(&As[(wr * 64 + m * 16 + l15) * 64 + slot]);
        bf[m][kk] = ldl8(&Bs[(wc * 64 + m * 16 + l15) * 64 + slot]);
      }
    }
#pragma unroll
    for (int m = 0; m < 4; ++m)
#pragma unroll
      for (int n = 0; n < 4; ++n)
#pragma unroll
        for (int kk = 0; kk < 2; ++kk)
          acc[m][n] = __builtin_amdgcn_mfma_f32_16x16x32_bf16(af[m][kk], bf[n][kk], acc[m][n], 0, 0, 0);
  }

#pragma unroll
  for (int n = 0; n < 4; ++n) {
    const int col = bn * 128 + wc * 64 + n * 16 + l15;
    const bool cok = col < Nstore;
    const float bv = (cok && bias) ? bias[col] : 0.f;
#pragma unroll
    for (int m = 0; m < 4; ++m) {
#pragma unroll
      for (int r = 0; r < 4; ++r) {
        const int row = bm * 128 + wr * 64 + m * 16 + l4 * 4 + r;
        if (cok) outf[(size_t)row * ldc + col] = acc[m][n][r] + bv;
      }
    }
  }
}

// ---------------------------------------------------------------------------
// Flash attention (unchanged)
// ---------------------------------------------------------------------------
__global__ __launch_bounds__(256, 3) void attn_flash(
    const u16* __restrict__ qkv, const u16* __restrict__ vt, u16* __restrict__ o)
{
  __shared__ u16 Kl[2][64 * 64];
  __shared__ u16 Vl[2][64 * 64];
  __shared__ u16 Pl[4][16 * 64];
  const int qt = blockIdx.x, h = blockIdx.y, b = blockIdx.z;
  const int lane = threadIdx.x & 63, w = threadIdx.x >> 6;
  const int l15 = lane & 15, l4 = lane >> 4;

  const size_t qoff = (size_t)(b * Ss + qt * 64 + w * 16 + l15) * QKVld + h * Dh + l4 * 8;
  const bf16x8 aq0 = ldg8(qkv + qoff), aq1 = ldg8(qkv + qoff + 32);

  const u16* kg = qkv + (size_t)b * Ss * QKVld + 1024 + h * Dh;
  const u16* vg = vt + (size_t)(b * NHd + h) * Dh * Ss;

  int srow[2], scs[2];
#pragma unroll
  for (int i = 0; i < 2; ++i) {
    srow[i] = (w * 2 + i) * 8 + (lane >> 3);
    scs[i] = ((lane & 7) ^ (srow[i] & 7)) * 8;
  }

  float m[4] = {-1e30f, -1e30f, -1e30f, -1e30f};
  float lsum[4] = {0.f, 0.f, 0.f, 0.f};
  f32x4 oa[4] = {};

  auto stage = [&](int bsel, int kb) {
#pragma unroll
    for (int i = 0; i < 2; ++i) {
      gload_lds16(kg + (size_t)(kb * 64 + srow[i]) * QKVld + scs[i], &Kl[bsel][(w * 2 + i) * 8 * 64]);
      gload_lds16(vg + (size_t)srow[i] * Ss + kb * 64 + scs[i], &Vl[bsel][(w * 2 + i) * 8 * 64]);
    }
  };

  stage(0, 0);
  __syncthreads();
  int buf = 0;
  for (int kb = 0; kb <= qt; ++kb) {
    if (kb < qt) stage(buf ^ 1, kb + 1);

    f32x4 sc[4];
    __builtin_amdgcn_s_setprio(1);
#pragma unroll
    for (int fj = 0; fj < 4; ++fj) {
      const u16* kp = &Kl[buf][(fj * 16 + l15) * 64];
      const int r7 = l15 & 7;
      bf16x8 kf0 = ldl8(kp + ((l4 ^ r7) << 3));
      bf16x8 kf1 = ldl8(kp + (((4 + l4) ^ r7) << 3));
      f32x4 zz = {};
      zz = __builtin_amdgcn_mfma_f32_16x16x32_bf16(aq0, kf0, zz, 0, 0, 0);
      sc[fj] = __builtin_amdgcn_mfma_f32_16x16x32_bf16(aq1, kf1, zz, 0, 0, 0);
    }
    __builtin_amdgcn_s_setprio(0);

    float pm[4] = {-1e30f, -1e30f, -1e30f, -1e30f};
    const bool diag = (kb == qt);
#pragma unroll
    for (int fj = 0; fj < 4; ++fj)
#pragma unroll
      for (int r = 0; r < 4; ++r) {
        float s = sc[fj][r] * 0.125f;
        if (diag && (fj * 16 + l15) > (w * 16 + l4 * 4 + r)) s = -1e30f;
        sc[fj][r] = s;
        pm[r] = fmaxf(pm[r], s);
      }
#pragma unroll
    for (int d = 1; d < 16; d <<= 1)
#pragma unroll
      for (int r = 0; r < 4; ++r) pm[r] = fmaxf(pm[r], __shfl_xor(pm[r], d));

    float al[4], ps[4];
#pragma unroll
    for (int r = 0; r < 4; ++r) {
      float mn = fmaxf(m[r], pm[r]);
      al[r] = __expf(m[r] - mn);
      m[r] = mn;
      ps[r] = 0.f;
    }
#pragma unroll
    for (int fj = 0; fj < 4; ++fj)
#pragma unroll
      for (int r = 0; r < 4; ++r) {
        float p = __expf(sc[fj][r] - m[r]);
        sc[fj][r] = p;
        ps[r] += p;
      }
#pragma unroll
    for (int d = 1; d < 16; d <<= 1)
#pragma unroll
      for (int r = 0; r < 4; ++r) ps[r] += __shfl_xor(ps[r], d);
#pragma unroll
    for (int r = 0; r < 4; ++r) lsum[r] = lsum[r] * al[r] + ps[r];
#pragma unroll
    for (int fn = 0; fn < 4; ++fn)
#pragma unroll
      for (int r = 0; r < 4; ++r) oa[fn][r] *= al[r];

#pragma unroll
    for (int fj = 0; fj < 4; ++fj)
#pragma unroll
      for (int r = 0; r < 4; ++r) {
        const int key = fj * 16 + l15, qloc = l4 * 4 + r;
        Pl[w][qloc * 64 + (((key >> 3) ^ (qloc & 7)) << 3) + (key & 7)] = f2bf(sc[fj][r]);
      }

    const int q7 = l15 & 7;
    bf16x8 pa0 = ldl8(&Pl[w][l15 * 64 + ((l4 ^ q7) << 3)]);
    bf16x8 pa1 = ldl8(&Pl[w][l15 * 64 + (((4 + l4) ^ q7) << 3)]);
    __builtin_amdgcn_s_setprio(1);
#pragma unroll
    for (int fn = 0; fn < 4; ++fn) {
      const u16* vp = &Vl[buf][(fn * 16 + l15) * 64];
      bf16x8 vf0 = ldl8(vp + ((l4 ^ q7) << 3));
      bf16x8 vf1 = ldl8(vp + (((4 + l4) ^ q7) << 3));
      oa[fn] = __builtin_amdgcn_mfma_f32_16x16x32_bf16(pa0, vf0, oa[fn], 0, 0, 0);
      oa[fn] = __builtin_amdgcn_mfma_f32_16x16x32_bf16(pa1, vf1, oa[fn], 0, 0, 0);
    }
    __builtin_amdgcn_s_setprio(0);
    __syncthreads();
    buf ^= 1;
  }

#pragma unroll
  for (int fn = 0; fn < 4; ++fn)
#pragma unroll
    for (int r = 0; r < 4; ++r) {
      const int row = b * Ss + qt * 64 + w * 16 + l4 * 4 + r;
      o[(size_t)row * Hh + h * Dh + fn * 16 + l15] = f2bf(oa[fn][r] / lsum[r]);
    }
}

// ---------------------------------------------------------------------------
// Embedding + interleave + LayerNorm -> h (fp32) and x (bf16)
// ---------------------------------------------------------------------------
__global__ __launch_bounds__(256) void embed_ln(
    const int* __restrict__ timesteps, const int* __restrict__ states,
    const int* __restrict__ actions, const float* __restrict__ rtg,
    const float* __restrict__ Wt, const float* __restrict__ Ws,
    const float* __restrict__ Wa, const float* __restrict__ Wr,
    const float* __restrict__ br, const float* __restrict__ lng,
    const float* __restrict__ lnb, float* __restrict__ hout, u16* __restrict__ xb)
{
  __shared__ float red[8];
  const int s = blockIdx.x;
  const int b = s / Ss, sl = s % Ss;
  const int tt = sl / 3, kind = sl % 3;
  const int bt = b * Tt + tt;
  const int e = threadIdx.x * 4;

  const float4 tv = *(const float4*)(Wt + (size_t)timesteps[bt] * Hh + e);
  float v[4];
  if (kind == 0) {
    const float rr = rtg[bt];
    const float4 w4 = *(const float4*)(Wr + e);
    const float4 b4 = *(const float4*)(br + e);
    v[0] = rr * w4.x + b4.x + tv.x; v[1] = rr * w4.y + b4.y + tv.y;
    v[2] = rr * w4.z + b4.z + tv.z; v[3] = rr * w4.w + b4.w + tv.w;
  } else {
    const float* emb = (kind == 1) ? (Ws + (size_t)states[bt] * Hh)
                                   : (Wa + (size_t)actions[bt] * Hh);
    const float4 e4 = *(const float4*)(emb + e);
    v[0] = e4.x + tv.x; v[1] = e4.y + tv.y; v[2] = e4.z + tv.z; v[3] = e4.w + tv.w;
  }
  float s1 = v[0] + v[1] + v[2] + v[3];
  float s2 = v[0]*v[0] + v[1]*v[1] + v[2]*v[2] + v[3]*v[3];
#pragma unroll
  for (int d = 32; d; d >>= 1) { s1 += __shfl_xor(s1, d); s2 += __shfl_xor(s2, d); }
  if ((threadIdx.x & 63) == 0) { red[threadIdx.x >> 6] = s1; red[4 + (threadIdx.x >> 6)] = s2; }
  __syncthreads();
  s1 = red[0] + red[1] + red[2] + red[3];
  s2 = red[4] + red[5] + red[6] + red[7];
  const float mean = s1 * (1.f / 1024.f);
  const float var = s2 * (1.f / 1024.f) - mean * mean;
  const float rs = rsqrtf(var + 1e-5f);
  const float4 g4 = *(const float4*)(lng + e);
  const float4 bb4 = *(const float4*)(lnb + e);
  float o0 = (v[0] - mean) * rs * g4.x + bb4.x;
  float o1 = (v[1] - mean) * rs * g4.y + bb4.y;
  float o2 = (v[2] - mean) * rs * g4.z + bb4.z;
  float o3 = (v[3] - mean) * rs * g4.w + bb4.w;
  *(float4*)(hout + (size_t)s * Hh + e) = make_float4(o0, o1, o2, o3);
  u16x4 ov = {f2bf(o0), f2bf(o1), f2bf(o2), f2bf(o3)};
  *(u16x4*)(xb + (size_t)s * Hh + e) = ov;
}

// ---------------------------------------------------------------------------
// Generalized LayerNorm (R19: bf16 partials): v = bf(pA)+bf(pB)+resid+bias;
// out h fp32 + x bf16.
// ---------------------------------------------------------------------------
__global__ __launch_bounds__(256) void ln_kernel(
    const u16* __restrict__ pA, const u16* __restrict__ pB,
    const float* __restrict__ resid, const float* __restrict__ bias,
    const float* __restrict__ g, const float* __restrict__ bta,
    float* __restrict__ hout, u16* __restrict__ xb)
{
  __shared__ float red[8];
  const int row = blockIdx.x;
  const int e = threadIdx.x * 4;
  const u16x4 a4 = *(const u16x4*)(pA + (size_t)row * Hh + e);
  float v[4] = {bf2f(a4[0]), bf2f(a4[1]), bf2f(a4[2]), bf2f(a4[3])};
  if (pB) {
    const u16x4 b4 = *(const u16x4*)(pB + (size_t)row * Hh + e);
    v[0] += bf2f(b4[0]); v[1] += bf2f(b4[1]); v[2] += bf2f(b4[2]); v[3] += bf2f(b4[3]);
  }
  if (resid) {
    const float4 r4 = *(const float4*)(resid + (size_t)row * Hh + e);
    v[0] += r4.x; v[1] += r4.y; v[2] += r4.z; v[3] += r4.w;
  }
  if (bias) {
    const float4 c4 = *(const float4*)(bias + e);
    v[0] += c4.x; v[1] += c4.y; v[2] += c4.z; v[3] += c4.w;
  }
  float s1 = v[0] + v[1] + v[2] + v[3];
  float s2 = v[0]*v[0] + v[1]*v[1] + v[2]*v[2] + v[3]*v[3];
#pragma unroll
  for (int d = 32; d; d >>= 1) { s1 += __shfl_xor(s1, d); s2 += __shfl_xor(s2, d); }
  if ((threadIdx.x & 63) == 0) { red[threadIdx.x >> 6] = s1; red[4 + (threadIdx.x >> 6)] = s2; }
  __syncthreads();
  s1 = red[0] + red[1] + red[2] + red[3];
  s2 = red[4] + red[5] + red[6] + red[7];
  const float mean = s1 * (1.f / 1024.f);
  const float var = s2 * (1.f / 1024.f) - mean * mean;
  const float rs = rsqrtf(var + 1e-5f);
  const float4 g4 = *(const float4*)(g + e);
  const float4 b4 = *(const float4*)(bta + e);
  float o0 = (v[0] - mean) * rs * g4.x + b4.x;
  float o1 = (v[1] - mean) * rs * g4.y + b4.y;
  float o2 = (v[2] - mean) * rs * g4.z + b4.z;
  float o3 = (v[3] - mean) * rs * g4.w + b4.w;
  *(float4*)(hout + (size_t)row * Hh + e) = make_float4(o0, o1, o2, o3);
  u16x4 ov = {f2bf(o0), f2bf(o1), f2bf(o2), f2bf(o3)};
  *(u16x4*)(xb + (size_t)row * Hh + e) = ov;
}

// W [Kd,Nd] fp32  ->  Wt [Nout,Kd] bf16 (rows >= Nd zero-padded)
__global__ __launch_bounds__(256) void transpose_w(
    const float* __restrict__ W, u16* __restrict__ Wt, int Kd, int Nd, int Nout)
{
  __shared__ float tile[32][33];
  const int k0 = blockIdx.x * 32, n0 = blockIdx.y * 32;
  const int tx = threadIdx.x & 31, ty = threadIdx.x >> 5;
#pragma unroll
  for (int rr = 0; rr < 4; ++rr) {
    const int kk = ty + rr * 8;
    const int n = n0 + tx;
    tile[kk][tx] = (n < Nd) ? W[(size_t)(k0 + kk) * Nd + n] : 0.f;
  }
  __syncthreads();
#pragma unroll
  for (int rr = 0; rr < 4; ++rr) {
    Wt[(size_t)(n0 + ty + rr * 8) * Kd + k0 + tx] = f2bf(tile[tx][ty + rr * 8]);
  }
}

// ---------------------------------------------------------------------------
// Fused per-layer weight transpose: all 6 matrices in ONE launch (R16).
// ---------------------------------------------------------------------------
__global__ __launch_bounds__(256) void transpose_all(
    const float* __restrict__ Wq, const float* __restrict__ Wk,
    const float* __restrict__ Wv, const float* __restrict__ Wp,
    const float* __restrict__ W1, const float* __restrict__ W2,
    u16* __restrict__ W3T, u16* __restrict__ WpT,
    u16* __restrict__ W1T, u16* __restrict__ W2T)
{
  __shared__ float tile[32][33];
  const int t = blockIdx.x;
  const float* src;
  u16* dst;
  int Kd, Nd, ti;
  if (t < 4096) {
    const int which = t >> 10;
    ti = t & 1023;
    Kd = 1024; Nd = 1024;
    src = (which == 0) ? Wq : (which == 1) ? Wk : (which == 2) ? Wv : Wp;
    dst = (which == 3) ? WpT : (W3T + (size_t)which * 1024 * 1024);
  } else if (t < 8192) {
    ti = t - 4096; Kd = 1024; Nd = 4096; src = W1; dst = W1T;
  } else {
    ti = t - 8192; Kd = 4096; Nd = 1024; src = W2; dst = W2T;
  }
  const int tilesK = Kd >> 5;
  const int k0 = (ti % tilesK) * 32, n0 = (ti / tilesK) * 32;
  const int tx = threadIdx.x & 31, ty = threadIdx.x >> 5;
#pragma unroll
  for (int rr = 0; rr < 4; ++rr) {
    const int kk = ty + rr * 8;
    tile[kk][tx] = src[(size_t)(k0 + kk) * Nd + n0 + tx];
  }
  __syncthreads();
#pragma unroll
  for (int rr = 0; rr < 4; ++rr) {
    dst[(size_t)(n0 + ty + rr * 8) * Kd + k0 + tx] = f2bf(tile[tx][ty + rr * 8]);
  }
}

// rtg head
__global__ __launch_bounds__(256) void rtg_head(
    const float* __restrict__ h, const float* __restrict__ Wr1,
    const float* __restrict__ br1, float* __restrict__ out)
{
  const int lane = threadIdx.x & 63, w = threadIdx.x >> 6;
  const int row = blockIdx.x * 4 + w;
  const int b = row >> 8, tt = row & 255;
  const float* x = h + (size_t)(b * Ss + 512 + tt) * Hh;
  float s = 0.f;
  for (int e = lane; e < Hh; e += 64) s += x[e] * Wr1[e];
#pragma unroll
  for (int d = 32; d; d >>= 1) s += __shfl_xor(s, d);
  if (lane == 0) out[row] = s + br1[0];
}

// ---------------------------------------------------------------------------
extern "C" void kernel_launch(void* const* d_in, const int* in_sizes, int n_in,
                              void* d_out, int out_size, void* d_ws, size_t ws_size,
                              hipStream_t stream)
{
  (void)in_sizes; (void)n_in; (void)out_size; (void)ws_size;
  const int*   timesteps = (const int*)d_in[0];
  const int*   states    = (const int*)d_in[1];
  const int*   actions   = (const int*)d_in[2];
  const float* rtg       = (const float*)d_in[3];
  const float* Wt   = (const float*)d_in[4];
  const float* Ws   = (const float*)d_in[5];
  const float* Wa   = (const float*)d_in[6];
  const float* Wr   = (const float*)d_in[7];
  const float* br   = (const float*)d_in[8];
  const float* lng  = (const float*)d_in[9];
  const float* lnb  = (const float*)d_in[10];
  const float* Wq   = (const float*)d_in[11];
  const float* bq   = (const float*)d_in[12];
  const float* Wk   = (const float*)d_in[13];
  const float* bk   = (const float*)d_in[14];
  const float* Wv   = (const float*)d_in[15];
  const float* bv   = (const float*)d_in[16];
  const float* Wp   = (const float*)d_in[17];
  const float* bp   = (const float*)d_in[18];
  const float* W1   = (const float*)d_in[19];
  const float* b1   = (const float*)d_in[20];
  const float* W2   = (const float*)d_in[21];
  const float* b2   = (const float*)d_in[22];
  const float* ln1g = (const float*)d_in[23];
  const float* ln1b = (const float*)d_in[24];
  const float* ln2g = (const float*)d_in[25];
  const float* ln2b = (const float*)d_in[26];
  const float* Wrtg = (const float*)d_in[27];
  const float* brtg = (const float*)d_in[28];
  const float* Wst  = (const float*)d_in[29];
  const float* bst  = (const float*)d_in[30];
  const float* Wac  = (const float*)d_in[31];
  const float* bac  = (const float*)d_in[32];

  char* wp = (char*)d_ws;
  auto alloc = [&](size_t bytes) { void* p = wp; wp += (bytes + 511) & ~(size_t)511; return p; };
  float* hbuf = (float*)alloc((size_t)BSr * Hh * 4);
  u16* pb   = (u16*)alloc((size_t)2 * BSr * Hh * 2);   // bf16 split-K partials
  u16* xb   = (u16*)alloc((size_t)BSr * Hh * 2);
  u16* qkvb = (u16*)alloc((size_t)BSr * QKVld * 2);
  u16* vtb  = (u16*)alloc((size_t)BSr * Hh * 2);
  u16* ob   = (u16*)alloc((size_t)BSr * Hh * 2);
  u16* ub   = (u16*)alloc((size_t)BSr * FFd * 2);
  u16* W3T  = (u16*)alloc((size_t)3 * Hh * Hh * 2);
  u16* WpT  = (u16*)alloc((size_t)Hh * Hh * 2);
  u16* W1T  = (u16*)alloc((size_t)FFd * Hh * 2);
  u16* W2T  = (u16*)alloc((size_t)Hh * FFd * 2);
  u16* WstT = (u16*)alloc((size_t)Hh * Hh * 2);
  u16* WacT = (u16*)alloc((size_t)128 * Hh * 2);

  float* out_state = (float*)d_out;
  float* out_act   = out_state + (size_t)2048 * 1024;
  float* out_rtg   = out_act + (size_t)2048 * 64;

  const size_t PSZ = (size_t)BSr * Hh;

  transpose_w<<<dim3(32, 32, 1), 256, 0, stream>>>(Wst, WstT, 1024, 1024, 1024);
  transpose_w<<<dim3(32, 4, 1), 256, 0, stream>>>(Wac, WacT, 1024, 64, 128);
  embed_ln<<<BSr, 256, 0, stream>>>(timesteps, states, actions, rtg, Wt, Ws, Wa, Wr,
                                    br, lng, lnb, hbuf, xb);

  for (int l = 0; l < Ll; ++l) {
    transpose_all<<<12288, 256, 0, stream>>>(
        Wq + (size_t)l * Hh * Hh, Wk + (size_t)l * Hh * Hh,
        Wv + (size_t)l * Hh * Hh, Wp + (size_t)l * Hh * Hh,
        W1 + (size_t)l * Hh * FFd, W2 + (size_t)l * FFd * Hh,
        W3T, WpT, W1T, W2T);

    // fused QKV: [6144,1024] x [1024,3072] -> qkvb (Q,K) + vtb (V transposed)
    gemm_db<<<dim3(24, 48, 1), 256, 0, stream>>>(
        xb, W3T, bq + l * Hh, bk + l * Hh, bv + l * Hh, nullptr, qkvb, vtb,
        Hh, Hh, QKVld, 0, 0);
    attn_flash<<<dim3(12, 16, 8), 256, 0, stream>>>(qkvb, vtb, ob);
    // attn out projection, split-K=2 -> bf16 partials pb[0],pb[1]
    gemm_db<<<dim3(8, 48, 2), 256, 0, stream>>>(
        ob, WpT, nullptr, nullptr, nullptr, nullptr, pb, nullptr,
        Hh, 512, Hh, 0, PSZ);
    ln_kernel<<<BSr, 256, 0, stream>>>(pb, pb + PSZ, hbuf, bp + l * Hh,
                                       ln1g + l * Hh, ln1b + l * Hh, hbuf, xb);
    // FFN1: [6144,1024] x [1024,4096], GELU -> ub bf16
    gemm_db<<<dim3(32, 48, 1), 256, 0, stream>>>(
        xb, W1T, b1 + l * FFd, nullptr, nullptr, nullptr, ub, nullptr,
        Hh, Hh, FFd, 1, 0);
    // FFN2: [6144,4096] x [4096,1024], split-K=2 -> bf16 partials
    gemm_db<<<dim3(8, 48, 2), 256, 0, stream>>>(
        ub, W2T, nullptr, nullptr, nullptr, nullptr, pb, nullptr,
        FFd, 2048, Hh, 0, PSZ);
    ln_kernel<<<BSr, 256, 0, stream>>>(pb, pb + PSZ, hbuf, b2 + l * Hh,
                                       ln2g + l * Hh, ln2b + l * Hh, hbuf, xb);
  }

  gemm_bf16<<<dim3(8, 16), 256, 0, stream>>>(xb, WstT, bst, out_state,
                                             2048, 1024, 1024, 1024, 1024, 1, 512);
  gemm_bf16<<<dim3(1, 16), 256, 0, stream>>>(xb, WacT, bac, out_act,
                                             2048, 128, 1024, 64, 64, 1, 256);
  rtg_head<<<512, 256, 0, stream>>>(hbuf, Wrtg, brtg, out_rtg);
}

// Round 20
// 1968.812 us; speedup vs baseline: 1.1084x; 1.0335x over previous
//
#include <hip/hip_runtime.h>
#include <hip/hip_bf16.h>

#define DI __device__ __forceinline__

typedef unsigned short u16;
typedef __bf16 bf16x8 __attribute__((ext_vector_type(8)));
typedef unsigned short u16x8 __attribute__((ext_vector_type(8)));
typedef unsigned short u16x4 __attribute__((ext_vector_type(4)));
typedef float f32x4 __attribute__((ext_vector_type(4)));

static constexpr int Bb = 8, Tt = 256, Hh = 1024, Ll = 6, NHd = 16, Dh = 64;
static constexpr int Ss = 3 * Tt;      // 768 tokens
static constexpr int FFd = 4096;
static constexpr int BSr = Bb * Ss;    // 6144 rows
static constexpr int QKVld = 3072;     // fused qkv row stride

DI u16 f2bf(float f) {
  unsigned u = __builtin_bit_cast(unsigned, f);
  u += 0x7fffu + ((u >> 16) & 1u);
  return (u16)(u >> 16);
}
DI float bf2f(u16 h) { return __builtin_bit_cast(float, (unsigned)h << 16); }

// tanh-form GELU (max |diff| vs erf-GELU ~3e-3, well under 7e-2 threshold)
DI float gelu_f(float x) {
  const float s = 1.5957691216f * x + 0.0713564814f * x * x * x;
  return x / (1.f + __expf(-s));
}

DI void gload_lds16(const u16* g, u16* l) {
  __builtin_amdgcn_global_load_lds((__attribute__((address_space(1))) void*)(g),
                                   (__attribute__((address_space(3))) void*)(l), 16, 0, 0);
}
DI bf16x8 ldl8(const u16* p) { return __builtin_bit_cast(bf16x8, *(const u16x8*)p); }
DI bf16x8 ldg8(const u16* p) { return __builtin_bit_cast(bf16x8, *(const u16x8*)p); }

DI void barRaw() {
  asm volatile("" ::: "memory");
  __builtin_amdgcn_s_barrier();
  asm volatile("" ::: "memory");
}

// ---------------------------------------------------------------------------
// GEMM: 128x128 tile, BK=64, 4 waves, double-buffered LDS (64 KiB, 2/CU).
// K-loop unrolled x2 static bases (R15); coalesced LDS-staged epilogue (R12,
// stride-130 C-tile); 2D-patch XCD swizzle (R13); tanh-GELU (R15); fused
// V-transpose for QKV (R18); bf16 split-K-capable outb path (R19).
// ---------------------------------------------------------------------------
__global__ __launch_bounds__(256, 2) void gemm_db(
    const u16* __restrict__ A, const u16* __restrict__ Bt,
    const float* __restrict__ bias, const float* __restrict__ bias2,
    const float* __restrict__ bias3,
    float* __restrict__ outf, u16* __restrict__ outb, u16* __restrict__ vt,
    int Kstride, int Ksub, int ldc, int act, size_t psz)
{
  __shared__ u16 SM[32768];   // 64 KiB: A0@0, A1@8192, B0@16384, B1@24576
  const int lane = threadIdx.x & 63, w = threadIdx.x >> 6;
  const int wr = w >> 1, wc = w & 1;
  const int l15 = lane & 15, l4 = lane >> 4;

  // bijective XCD swizzle (m204) + 2D patch mapping (CG=8 cols, bn fastest)
  const int gx = gridDim.x, gy = gridDim.y, nwg = gx * gy;
  int f = blockIdx.y * gx + blockIdx.x;
  { int q = nwg >> 3, rr = nwg & 7, x = f & 7, idx = f >> 3;
    f = (x < rr ? x * (q + 1) : rr * (q + 1) + (x - rr) * q) + idx; }
  const int r2 = f % (gy * 8), cg = f / (gy * 8);
  const int bm = r2 >> 3, bn = cg * 8 + (r2 & 7);
  const int koff = blockIdx.z * Ksub;
  const int NT = Ksub >> 6;   // even for all uses (16 / 64 / 16)

  const int srow = lane >> 3;
  const int schunk = ((lane & 7) ^ srow) << 3;
  unsigned aoff[4], boff[4];
#pragma unroll
  for (int i = 0; i < 4; ++i) {
    const int r = w * 32 + i * 8 + srow;
    aoff[i] = (unsigned)(bm * 128 + r) * (unsigned)Kstride + koff + schunk;
    boff[i] = (unsigned)(bn * 128 + r) * (unsigned)Kstride + koff + schunk;
  }

  auto stage = [&](int bsel, int kt) {
#pragma unroll
    for (int i = 0; i < 4; ++i)
      gload_lds16(A + aoff[i] + kt * 64, &SM[bsel * 8192 + (w * 32 + i * 8) * 64]);
#pragma unroll
    for (int i = 0; i < 4; ++i)
      gload_lds16(Bt + boff[i] + kt * 64, &SM[16384 + bsel * 8192 + (w * 32 + i * 8) * 64]);
  };

  f32x4 acc[4][4] = {};
  const int r7 = l15 & 7;

  auto body = [&](int CB, int tn, bool more) {
    if (more) stage(CB ^ 1, tn);
    bf16x8 af[4][2], bf[4][2];
#pragma unroll
    for (int m = 0; m < 4; ++m) {
#pragma unroll
      for (int kk = 0; kk < 2; ++kk) {
        const int slot = (((kk * 4 + l4) ^ r7) << 3);
        af[m][kk] = ldl8(&SM[CB * 8192 + (wr * 64 + m * 16 + l15) * 64 + slot]);
        bf[m][kk] = ldl8(&SM[16384 + CB * 8192 + (wc * 64 + m * 16 + l15) * 64 + slot]);
      }
    }
    __builtin_amdgcn_s_setprio(1);
#pragma unroll
    for (int kk = 0; kk < 2; ++kk)
#pragma unroll
      for (int m = 0; m < 4; ++m)
#pragma unroll
        for (int n = 0; n < 4; ++n)
          acc[m][n] = __builtin_amdgcn_mfma_f32_16x16x32_bf16(af[m][kk], bf[n][kk], acc[m][n], 0, 0, 0);
    __builtin_amdgcn_s_setprio(0);
    if (more) asm volatile("s_waitcnt vmcnt(0)" ::: "memory");  // aged drain
    barRaw();
  };

  stage(0, 0);
  asm volatile("s_waitcnt vmcnt(0)" ::: "memory");
  barRaw();

  for (int t = 0; t < NT; t += 2) {
    body(0, t + 1, t + 1 < NT);
    body(1, t + 2, t + 2 < NT);
  }

  // ---- coalesced epilogue via LDS staging (C-tile stride 130 u16) ----
  if (outb) {
#pragma unroll
    for (int n = 0; n < 4; ++n) {
      const int col = wc * 64 + n * 16 + l15;
      const int gcol = bn * 128 + col;
      float bval = 0.f;
      if (bias) {
        const float* bp_ = bias;
        int idx = gcol;
        if (bias2 && gcol >= 1024) { bp_ = (gcol >= 2048) ? bias3 : bias2; idx = gcol & 1023; }
        bval = bp_[idx];
      }
#pragma unroll
      for (int m = 0; m < 4; ++m) {
#pragma unroll
        for (int r = 0; r < 4; ++r) {
          const int lrow = wr * 64 + m * 16 + l4 * 4 + r;
          float x = acc[m][n][r] + bval;
          if (act) x = gelu_f(x);
          SM[lrow * 130 + col] = f2bf(x);
        }
      }
    }
    barRaw();
    if (vt && bn >= 16) {
      // V tile: write transposed into vt[B,NH,D,S].
      const int bb = bm / 6, s0 = (bm % 6) * 128;
      const int c = threadIdx.x & 127, sh = threadIdx.x >> 7;
      const int h2 = (bn - 16) * 2 + (c >> 6), d = c & 63;
      u16* dst = vt + ((size_t)(bb * NHd + h2) * Dh + d) * Ss + s0 + sh * 64;
#pragma unroll
      for (int jv = 0; jv < 8; ++jv) {
        u16x8 v8;
#pragma unroll
        for (int e = 0; e < 8; ++e)
          v8[e] = SM[(sh * 64 + jv * 8 + e) * 130 + c];
        *(u16x8*)&dst[jv * 8] = v8;
      }
    } else {
      u16* ob2 = outb + blockIdx.z * psz;
#pragma unroll 4
      for (int rr2 = 0; rr2 < 32; ++rr2) {
        const int row = rr2 * 4 + w;
        *(unsigned*)&ob2[(size_t)(bm * 128 + row) * ldc + bn * 128 + lane * 2] =
            *(const unsigned*)&SM[row * 130 + lane * 2];
      }
    }
  } else if (outf) {
    float* Cf = (float*)SM;
#pragma unroll
    for (int half = 0; half < 2; ++half) {
      barRaw();
      if (wr == half) {
#pragma unroll
        for (int n = 0; n < 4; ++n) {
          const int col = wc * 64 + n * 16 + l15;
          const int gcol = bn * 128 + col;
          float bval = 0.f;
          if (bias) {
            const float* bp_ = bias;
            int idx = gcol;
            if (bias2 && gcol >= 1024) { bp_ = (gcol >= 2048) ? bias3 : bias2; idx = gcol & 1023; }
            bval = bp_[idx];
          }
#pragma unroll
          for (int m = 0; m < 4; ++m) {
#pragma unroll
            for (int r = 0; r < 4; ++r) {
              float x = acc[m][n][r] + bval;
              if (act) x = gelu_f(x);
              Cf[(m * 16 + l4 * 4 + r) * 128 + col] = x;
            }
          }
        }
      }
      barRaw();
#pragma unroll 4
      for (int rr2 = 0; rr2 < 16; ++rr2) {
        const int row = rr2 * 4 + w;
        *(float2*)&outf[blockIdx.z * psz +
                        (size_t)(bm * 128 + half * 64 + row) * ldc + bn * 128 + lane * 2] =
            *(const float2*)&Cf[row * 128 + lane * 2];
      }
    }
  }
}

// ---------------------------------------------------------------------------
// Small GEMM (heads): 128x128 tile, BK=64, 4 waves, 16x16 MFMA.
// ---------------------------------------------------------------------------
__global__ __launch_bounds__(256, 2) void gemm_bf16(
    const u16* __restrict__ A, const u16* __restrict__ Bt,
    const float* __restrict__ bias, float* __restrict__ outf,
    int M, int N, int K, int ldc, int Nstore, int rowmode, int rowoff)
{
  __shared__ u16 As[128 * 64];
  __shared__ u16 Bs[128 * 64];
  const int tid = threadIdx.x;
  const int lane = tid & 63;
  const int w = tid >> 6;
  const int wr = w >> 1, wc = w & 1;
  const int bn = blockIdx.x, bm = blockIdx.y;
  const int l3 = lane >> 3, l7 = lane & 7, l15 = lane & 15, l4 = lane >> 4;

  f32x4 acc[4][4] = {};

  const int schunk = (l7 ^ l3) << 3;
  size_t aoff[4], boff[4];
#pragma unroll
  for (int i = 0; i < 4; ++i) {
    int r = bm * 128 + w * 32 + i * 8 + l3;
    int ar = rowmode ? ((r >> 8) * Ss + rowoff + (r & 255)) : r;
    aoff[i] = (size_t)ar * K + schunk;
    boff[i] = (size_t)(bn * 128 + w * 32 + i * 8 + l3) * K + schunk;
  }

  for (int kt = 0; kt < K; kt += 64) {
    __syncthreads();
#pragma unroll
    for (int i = 0; i < 4; ++i) {
      gload_lds16(A + aoff[i] + kt, &As[(w * 32 + i * 8) * 64]);
      gload_lds16(Bt + boff[i] + kt, &Bs[(w * 32 + i * 8) * 64]);
    }
    __syncthreads();

    bf16x8 af[4][2], bf[4][2];
#pragma unroll
    for (int m = 0; m < 4; ++m) {
#pragma unroll
      for (int kk = 0; kk < 2; ++kk) {
        const int slot = ((kk * 4 + l4) ^ l7) << 3;
        af[m][kk] = ldl8(&As[(wr * 64 + m * 16 + l15) * 64 + slot]);
        bf[m][kk] = ldl8(&Bs[(wc * 64 + m * 16 + l15) * 64 + slot]);
      }
    }
#pragma unroll
    for (int m = 0; m < 4; ++m)
#pragma unroll
      for (int n = 0; n < 4; ++n)
#pragma unroll
        for (int kk = 0; kk < 2; ++kk)
          acc[m][n] = __builtin_amdgcn_mfma_f32_16x16x32_bf16(af[m][kk], bf[n][kk], acc[m][n], 0, 0, 0);
  }

#pragma unroll
  for (int n = 0; n < 4; ++n) {
    const int col = bn * 128 + wc * 64 + n * 16 + l15;
    const bool cok = col < Nstore;
    const float bv = (cok && bias) ? bias[col] : 0.f;
#pragma unroll
    for (int m = 0; m < 4; ++m) {
#pragma unroll
      for (int r = 0; r < 4; ++r) {
        const int row = bm * 128 + wr * 64 + m * 16 + l4 * 4 + r;
        if (cok) outf[(size_t)row * ldc + col] = acc[m][n][r] + bv;
      }
    }
  }
}

// ---------------------------------------------------------------------------
// Flash attention (unchanged)
// ---------------------------------------------------------------------------
__global__ __launch_bounds__(256, 3) void attn_flash(
    const u16* __restrict__ qkv, const u16* __restrict__ vt, u16* __restrict__ o)
{
  __shared__ u16 Kl[2][64 * 64];
  __shared__ u16 Vl[2][64 * 64];
  __shared__ u16 Pl[4][16 * 64];
  const int qt = blockIdx.x, h = blockIdx.y, b = blockIdx.z;
  const int lane = threadIdx.x & 63, w = threadIdx.x >> 6;
  const int l15 = lane & 15, l4 = lane >> 4;

  const size_t qoff = (size_t)(b * Ss + qt * 64 + w * 16 + l15) * QKVld + h * Dh + l4 * 8;
  const bf16x8 aq0 = ldg8(qkv + qoff), aq1 = ldg8(qkv + qoff + 32);

  const u16* kg = qkv + (size_t)b * Ss * QKVld + 1024 + h * Dh;
  const u16* vg = vt + (size_t)(b * NHd + h) * Dh * Ss;

  int srow[2], scs[2];
#pragma unroll
  for (int i = 0; i < 2; ++i) {
    srow[i] = (w * 2 + i) * 8 + (lane >> 3);
    scs[i] = ((lane & 7) ^ (srow[i] & 7)) * 8;
  }

  float m[4] = {-1e30f, -1e30f, -1e30f, -1e30f};
  float lsum[4] = {0.f, 0.f, 0.f, 0.f};
  f32x4 oa[4] = {};

  auto stage = [&](int bsel, int kb) {
#pragma unroll
    for (int i = 0; i < 2; ++i) {
      gload_lds16(kg + (size_t)(kb * 64 + srow[i]) * QKVld + scs[i], &Kl[bsel][(w * 2 + i) * 8 * 64]);
      gload_lds16(vg + (size_t)srow[i] * Ss + kb * 64 + scs[i], &Vl[bsel][(w * 2 + i) * 8 * 64]);
    }
  };

  stage(0, 0);
  __syncthreads();
  int buf = 0;
  for (int kb = 0; kb <= qt; ++kb) {
    if (kb < qt) stage(buf ^ 1, kb + 1);

    f32x4 sc[4];
    __builtin_amdgcn_s_setprio(1);
#pragma unroll
    for (int fj = 0; fj < 4; ++fj) {
      const u16* kp = &Kl[buf][(fj * 16 + l15) * 64];
      const int r7 = l15 & 7;
      bf16x8 kf0 = ldl8(kp + ((l4 ^ r7) << 3));
      bf16x8 kf1 = ldl8(kp + (((4 + l4) ^ r7) << 3));
      f32x4 zz = {};
      zz = __builtin_amdgcn_mfma_f32_16x16x32_bf16(aq0, kf0, zz, 0, 0, 0);
      sc[fj] = __builtin_amdgcn_mfma_f32_16x16x32_bf16(aq1, kf1, zz, 0, 0, 0);
    }
    __builtin_amdgcn_s_setprio(0);

    float pm[4] = {-1e30f, -1e30f, -1e30f, -1e30f};
    const bool diag = (kb == qt);
#pragma unroll
    for (int fj = 0; fj < 4; ++fj)
#pragma unroll
      for (int r = 0; r < 4; ++r) {
        float s = sc[fj][r] * 0.125f;
        if (diag && (fj * 16 + l15) > (w * 16 + l4 * 4 + r)) s = -1e30f;
        sc[fj][r] = s;
        pm[r] = fmaxf(pm[r], s);
      }
#pragma unroll
    for (int d = 1; d < 16; d <<= 1)
#pragma unroll
      for (int r = 0; r < 4; ++r) pm[r] = fmaxf(pm[r], __shfl_xor(pm[r], d));

    float al[4], ps[4];
#pragma unroll
    for (int r = 0; r < 4; ++r) {
      float mn = fmaxf(m[r], pm[r]);
      al[r] = __expf(m[r] - mn);
      m[r] = mn;
      ps[r] = 0.f;
    }
#pragma unroll
    for (int fj = 0; fj < 4; ++fj)
#pragma unroll
      for (int r = 0; r < 4; ++r) {
        float p = __expf(sc[fj][r] - m[r]);
        sc[fj][r] = p;
        ps[r] += p;
      }
#pragma unroll
    for (int d = 1; d < 16; d <<= 1)
#pragma unroll
      for (int r = 0; r < 4; ++r) ps[r] += __shfl_xor(ps[r], d);
#pragma unroll
    for (int r = 0; r < 4; ++r) lsum[r] = lsum[r] * al[r] + ps[r];
#pragma unroll
    for (int fn = 0; fn < 4; ++fn)
#pragma unroll
      for (int r = 0; r < 4; ++r) oa[fn][r] *= al[r];

#pragma unroll
    for (int fj = 0; fj < 4; ++fj)
#pragma unroll
      for (int r = 0; r < 4; ++r) {
        const int key = fj * 16 + l15, qloc = l4 * 4 + r;
        Pl[w][qloc * 64 + (((key >> 3) ^ (qloc & 7)) << 3) + (key & 7)] = f2bf(sc[fj][r]);
      }

    const int q7 = l15 & 7;
    bf16x8 pa0 = ldl8(&Pl[w][l15 * 64 + ((l4 ^ q7) << 3)]);
    bf16x8 pa1 = ldl8(&Pl[w][l15 * 64 + (((4 + l4) ^ q7) << 3)]);
    __builtin_amdgcn_s_setprio(1);
#pragma unroll
    for (int fn = 0; fn < 4; ++fn) {
      const u16* vp = &Vl[buf][(fn * 16 + l15) * 64];
      bf16x8 vf0 = ldl8(vp + ((l4 ^ q7) << 3));
      bf16x8 vf1 = ldl8(vp + (((4 + l4) ^ q7) << 3));
      oa[fn] = __builtin_amdgcn_mfma_f32_16x16x32_bf16(pa0, vf0, oa[fn], 0, 0, 0);
      oa[fn] = __builtin_amdgcn_mfma_f32_16x16x32_bf16(pa1, vf1, oa[fn], 0, 0, 0);
    }
    __builtin_amdgcn_s_setprio(0);
    __syncthreads();
    buf ^= 1;
  }

#pragma unroll
  for (int fn = 0; fn < 4; ++fn)
#pragma unroll
    for (int r = 0; r < 4; ++r) {
      const int row = b * Ss + qt * 64 + w * 16 + l4 * 4 + r;
      o[(size_t)row * Hh + h * Dh + fn * 16 + l15] = f2bf(oa[fn][r] / lsum[r]);
    }
}

// ---------------------------------------------------------------------------
// Embedding + interleave + LayerNorm -> h (fp32) and x (bf16)
// ---------------------------------------------------------------------------
__global__ __launch_bounds__(256) void embed_ln(
    const int* __restrict__ timesteps, const int* __restrict__ states,
    const int* __restrict__ actions, const float* __restrict__ rtg,
    const float* __restrict__ Wt, const float* __restrict__ Ws,
    const float* __restrict__ Wa, const float* __restrict__ Wr,
    const float* __restrict__ br, const float* __restrict__ lng,
    const float* __restrict__ lnb, float* __restrict__ hout, u16* __restrict__ xb)
{
  __shared__ float red[8];
  const int s = blockIdx.x;
  const int b = s / Ss, sl = s % Ss;
  const int tt = sl / 3, kind = sl % 3;
  const int bt = b * Tt + tt;
  const int e = threadIdx.x * 4;

  const float4 tv = *(const float4*)(Wt + (size_t)timesteps[bt] * Hh + e);
  float v[4];
  if (kind == 0) {
    const float rr = rtg[bt];
    const float4 w4 = *(const float4*)(Wr + e);
    const float4 b4 = *(const float4*)(br + e);
    v[0] = rr * w4.x + b4.x + tv.x; v[1] = rr * w4.y + b4.y + tv.y;
    v[2] = rr * w4.z + b4.z + tv.z; v[3] = rr * w4.w + b4.w + tv.w;
  } else {
    const float* emb = (kind == 1) ? (Ws + (size_t)states[bt] * Hh)
                                   : (Wa + (size_t)actions[bt] * Hh);
    const float4 e4 = *(const float4*)(emb + e);
    v[0] = e4.x + tv.x; v[1] = e4.y + tv.y; v[2] = e4.z + tv.z; v[3] = e4.w + tv.w;
  }
  float s1 = v[0] + v[1] + v[2] + v[3];
  float s2 = v[0]*v[0] + v[1]*v[1] + v[2]*v[2] + v[3]*v[3];
#pragma unroll
  for (int d = 32; d; d >>= 1) { s1 += __shfl_xor(s1, d); s2 += __shfl_xor(s2, d); }
  if ((threadIdx.x & 63) == 0) { red[threadIdx.x >> 6] = s1; red[4 + (threadIdx.x >> 6)] = s2; }
  __syncthreads();
  s1 = red[0] + red[1] + red[2] + red[3];
  s2 = red[4] + red[5] + red[6] + red[7];
  const float mean = s1 * (1.f / 1024.f);
  const float var = s2 * (1.f / 1024.f) - mean * mean;
  const float rs = rsqrtf(var + 1e-5f);
  const float4 g4 = *(const float4*)(lng + e);
  const float4 bb4 = *(const float4*)(lnb + e);
  float o0 = (v[0] - mean) * rs * g4.x + bb4.x;
  float o1 = (v[1] - mean) * rs * g4.y + bb4.y;
  float o2 = (v[2] - mean) * rs * g4.z + bb4.z;
  float o3 = (v[3] - mean) * rs * g4.w + bb4.w;
  *(float4*)(hout + (size_t)s * Hh + e) = make_float4(o0, o1, o2, o3);
  u16x4 ov = {f2bf(o0), f2bf(o1), f2bf(o2), f2bf(o3)};
  *(u16x4*)(xb + (size_t)s * Hh + e) = ov;
}

// ---------------------------------------------------------------------------
// Generalized LayerNorm (bf16 partials): v = bf(pA)+bf(pB?)+resid+bias;
// out h fp32 + x bf16.
// ---------------------------------------------------------------------------
__global__ __launch_bounds__(256) void ln_kernel(
    const u16* __restrict__ pA, const u16* __restrict__ pB,
    const float* __restrict__ resid, const float* __restrict__ bias,
    const float* __restrict__ g, const float* __restrict__ bta,
    float* __restrict__ hout, u16* __restrict__ xb)
{
  __shared__ float red[8];
  const int row = blockIdx.x;
  const int e = threadIdx.x * 4;
  const u16x4 a4 = *(const u16x4*)(pA + (size_t)row * Hh + e);
  float v[4] = {bf2f(a4[0]), bf2f(a4[1]), bf2f(a4[2]), bf2f(a4[3])};
  if (pB) {
    const u16x4 b4 = *(const u16x4*)(pB + (size_t)row * Hh + e);
    v[0] += bf2f(b4[0]); v[1] += bf2f(b4[1]); v[2] += bf2f(b4[2]); v[3] += bf2f(b4[3]);
  }
  if (resid) {
    const float4 r4 = *(const float4*)(resid + (size_t)row * Hh + e);
    v[0] += r4.x; v[1] += r4.y; v[2] += r4.z; v[3] += r4.w;
  }
  if (bias) {
    const float4 c4 = *(const float4*)(bias + e);
    v[0] += c4.x; v[1] += c4.y; v[2] += c4.z; v[3] += c4.w;
  }
  float s1 = v[0] + v[1] + v[2] + v[3];
  float s2 = v[0]*v[0] + v[1]*v[1] + v[2]*v[2] + v[3]*v[3];
#pragma unroll
  for (int d = 32; d; d >>= 1) { s1 += __shfl_xor(s1, d); s2 += __shfl_xor(s2, d); }
  if ((threadIdx.x & 63) == 0) { red[threadIdx.x >> 6] = s1; red[4 + (threadIdx.x >> 6)] = s2; }
  __syncthreads();
  s1 = red[0] + red[1] + red[2] + red[3];
  s2 = red[4] + red[5] + red[6] + red[7];
  const float mean = s1 * (1.f / 1024.f);
  const float var = s2 * (1.f / 1024.f) - mean * mean;
  const float rs = rsqrtf(var + 1e-5f);
  const float4 g4 = *(const float4*)(g + e);
  const float4 b4 = *(const float4*)(bta + e);
  float o0 = (v[0] - mean) * rs * g4.x + b4.x;
  float o1 = (v[1] - mean) * rs * g4.y + b4.y;
  float o2 = (v[2] - mean) * rs * g4.z + b4.z;
  float o3 = (v[3] - mean) * rs * g4.w + b4.w;
  *(float4*)(hout + (size_t)row * Hh + e) = make_float4(o0, o1, o2, o3);
  u16x4 ov = {f2bf(o0), f2bf(o1), f2bf(o2), f2bf(o3)};
  *(u16x4*)(xb + (size_t)row * Hh + e) = ov;
}

// W [Kd,Nd] fp32  ->  Wt [Nout,Kd] bf16 (rows >= Nd zero-padded)
__global__ __launch_bounds__(256) void transpose_w(
    const float* __restrict__ W, u16* __restrict__ Wt, int Kd, int Nd, int Nout)
{
  __shared__ float tile[32][33];
  const int k0 = blockIdx.x * 32, n0 = blockIdx.y * 32;
  const int tx = threadIdx.x & 31, ty = threadIdx.x >> 5;
#pragma unroll
  for (int rr = 0; rr < 4; ++rr) {
    const int kk = ty + rr * 8;
    const int n = n0 + tx;
    tile[kk][tx] = (n < Nd) ? W[(size_t)(k0 + kk) * Nd + n] : 0.f;
  }
  __syncthreads();
#pragma unroll
  for (int rr = 0; rr < 4; ++rr) {
    Wt[(size_t)(n0 + ty + rr * 8) * Kd + k0 + tx] = f2bf(tile[tx][ty + rr * 8]);
  }
}

// ---------------------------------------------------------------------------
// Fused per-layer weight transpose: all 6 matrices in ONE launch (R16).
// ---------------------------------------------------------------------------
__global__ __launch_bounds__(256) void transpose_all(
    const float* __restrict__ Wq, const float* __restrict__ Wk,
    const float* __restrict__ Wv, const float* __restrict__ Wp,
    const float* __restrict__ W1, const float* __restrict__ W2,
    u16* __restrict__ W3T, u16* __restrict__ WpT,
    u16* __restrict__ W1T, u16* __restrict__ W2T)
{
  __shared__ float tile[32][33];
  const int t = blockIdx.x;
  const float* src;
  u16* dst;
  int Kd, Nd, ti;
  if (t < 4096) {
    const int which = t >> 10;
    ti = t & 1023;
    Kd = 1024; Nd = 1024;
    src = (which == 0) ? Wq : (which == 1) ? Wk : (which == 2) ? Wv : Wp;
    dst = (which == 3) ? WpT : (W3T + (size_t)which * 1024 * 1024);
  } else if (t < 8192) {
    ti = t - 4096; Kd = 1024; Nd = 4096; src = W1; dst = W1T;
  } else {
    ti = t - 8192; Kd = 4096; Nd = 1024; src = W2; dst = W2T;
  }
  const int tilesK = Kd >> 5;
  const int k0 = (ti % tilesK) * 32, n0 = (ti / tilesK) * 32;
  const int tx = threadIdx.x & 31, ty = threadIdx.x >> 5;
#pragma unroll
  for (int rr = 0; rr < 4; ++rr) {
    const int kk = ty + rr * 8;
    tile[kk][tx] = src[(size_t)(k0 + kk) * Nd + n0 + tx];
  }
  __syncthreads();
#pragma unroll
  for (int rr = 0; rr < 4; ++rr) {
    dst[(size_t)(n0 + ty + rr * 8) * Kd + k0 + tx] = f2bf(tile[tx][ty + rr * 8]);
  }
}

// rtg head
__global__ __launch_bounds__(256) void rtg_head(
    const float* __restrict__ h, const float* __restrict__ Wr1,
    const float* __restrict__ br1, float* __restrict__ out)
{
  const int lane = threadIdx.x & 63, w = threadIdx.x >> 6;
  const int row = blockIdx.x * 4 + w;
  const int b = row >> 8, tt = row & 255;
  const float* x = h + (size_t)(b * Ss + 512 + tt) * Hh;
  float s = 0.f;
  for (int e = lane; e < Hh; e += 64) s += x[e] * Wr1[e];
#pragma unroll
  for (int d = 32; d; d >>= 1) s += __shfl_xor(s, d);
  if (lane == 0) out[row] = s + br1[0];
}

// ---------------------------------------------------------------------------
extern "C" void kernel_launch(void* const* d_in, const int* in_sizes, int n_in,
                              void* d_out, int out_size, void* d_ws, size_t ws_size,
                              hipStream_t stream)
{
  (void)in_sizes; (void)n_in; (void)out_size; (void)ws_size;
  const int*   timesteps = (const int*)d_in[0];
  const int*   states    = (const int*)d_in[1];
  const int*   actions   = (const int*)d_in[2];
  const float* rtg       = (const float*)d_in[3];
  const float* Wt   = (const float*)d_in[4];
  const float* Ws   = (const float*)d_in[5];
  const float* Wa   = (const float*)d_in[6];
  const float* Wr   = (const float*)d_in[7];
  const float* br   = (const float*)d_in[8];
  const float* lng  = (const float*)d_in[9];
  const float* lnb  = (const float*)d_in[10];
  const float* Wq   = (const float*)d_in[11];
  const float* bq   = (const float*)d_in[12];
  const float* Wk   = (const float*)d_in[13];
  const float* bk   = (const float*)d_in[14];
  const float* Wv   = (const float*)d_in[15];
  const float* bv   = (const float*)d_in[16];
  const float* Wp   = (const float*)d_in[17];
  const float* bp   = (const float*)d_in[18];
  const float* W1   = (const float*)d_in[19];
  const float* b1   = (const float*)d_in[20];
  const float* W2   = (const float*)d_in[21];
  const float* b2   = (const float*)d_in[22];
  const float* ln1g = (const float*)d_in[23];
  const float* ln1b = (const float*)d_in[24];
  const float* ln2g = (const float*)d_in[25];
  const float* ln2b = (const float*)d_in[26];
  const float* Wrtg = (const float*)d_in[27];
  const float* brtg = (const float*)d_in[28];
  const float* Wst  = (const float*)d_in[29];
  const float* bst  = (const float*)d_in[30];
  const float* Wac  = (const float*)d_in[31];
  const float* bac  = (const float*)d_in[32];

  char* wp = (char*)d_ws;
  auto alloc = [&](size_t bytes) { void* p = wp; wp += (bytes + 511) & ~(size_t)511; return p; };
  float* hbuf = (float*)alloc((size_t)BSr * Hh * 4);
  u16* pb   = (u16*)alloc((size_t)BSr * Hh * 2);   // bf16 GEMM output (no split)
  u16* xb   = (u16*)alloc((size_t)BSr * Hh * 2);
  u16* qkvb = (u16*)alloc((size_t)BSr * QKVld * 2);
  u16* vtb  = (u16*)alloc((size_t)BSr * Hh * 2);
  u16* ob   = (u16*)alloc((size_t)BSr * Hh * 2);
  u16* ub   = (u16*)alloc((size_t)BSr * FFd * 2);
  u16* W3T  = (u16*)alloc((size_t)3 * Hh * Hh * 2);
  u16* WpT  = (u16*)alloc((size_t)Hh * Hh * 2);
  u16* W1T  = (u16*)alloc((size_t)FFd * Hh * 2);
  u16* W2T  = (u16*)alloc((size_t)Hh * FFd * 2);
  u16* WstT = (u16*)alloc((size_t)Hh * Hh * 2);
  u16* WacT = (u16*)alloc((size_t)128 * Hh * 2);

  float* out_state = (float*)d_out;
  float* out_act   = out_state + (size_t)2048 * 1024;
  float* out_rtg   = out_act + (size_t)2048 * 64;

  transpose_w<<<dim3(32, 32, 1), 256, 0, stream>>>(Wst, WstT, 1024, 1024, 1024);
  transpose_w<<<dim3(32, 4, 1), 256, 0, stream>>>(Wac, WacT, 1024, 64, 128);
  embed_ln<<<BSr, 256, 0, stream>>>(timesteps, states, actions, rtg, Wt, Ws, Wa, Wr,
                                    br, lng, lnb, hbuf, xb);

  for (int l = 0; l < Ll; ++l) {
    transpose_all<<<12288, 256, 0, stream>>>(
        Wq + (size_t)l * Hh * Hh, Wk + (size_t)l * Hh * Hh,
        Wv + (size_t)l * Hh * Hh, Wp + (size_t)l * Hh * Hh,
        W1 + (size_t)l * Hh * FFd, W2 + (size_t)l * FFd * Hh,
        W3T, WpT, W1T, W2T);

    // fused QKV: [6144,1024] x [1024,3072] -> qkvb (Q,K) + vtb (V transposed)
    gemm_db<<<dim3(24, 48, 1), 256, 0, stream>>>(
        xb, W3T, bq + l * Hh, bk + l * Hh, bv + l * Hh, nullptr, qkvb, vtb,
        Hh, Hh, QKVld, 0, 0);
    attn_flash<<<dim3(12, 16, 8), 256, 0, stream>>>(qkvb, vtb, ob);
    // attn out projection (no split-K, R20): bf16 -> pb
    gemm_db<<<dim3(8, 48, 1), 256, 0, stream>>>(
        ob, WpT, nullptr, nullptr, nullptr, nullptr, pb, nullptr,
        Hh, Hh, Hh, 0, 0);
    ln_kernel<<<BSr, 256, 0, stream>>>(pb, nullptr, hbuf, bp + l * Hh,
                                       ln1g + l * Hh, ln1b + l * Hh, hbuf, xb);
    // FFN1: [6144,1024] x [1024,4096], GELU -> ub bf16
    gemm_db<<<dim3(32, 48, 1), 256, 0, stream>>>(
        xb, W1T, b1 + l * FFd, nullptr, nullptr, nullptr, ub, nullptr,
        Hh, Hh, FFd, 1, 0);
    // FFN2: [6144,4096] x [4096,1024] (no split-K, NT=64): bf16 -> pb
    gemm_db<<<dim3(8, 48, 1), 256, 0, stream>>>(
        ub, W2T, nullptr, nullptr, nullptr, nullptr, pb, nullptr,
        FFd, FFd, Hh, 0, 0);
    ln_kernel<<<BSr, 256, 0, stream>>>(pb, nullptr, hbuf, b2 + l * Hh,
                                       ln2g + l * Hh, ln2b + l * Hh, hbuf, xb);
  }

  gemm_bf16<<<dim3(8, 16), 256, 0, stream>>>(xb, WstT, bst, out_state,
                                             2048, 1024, 1024, 1024, 1024, 1, 512);
  gemm_bf16<<<dim3(1, 16), 256, 0, stream>>>(xb, WacT, bac, out_act,
                                             2048, 128, 1024, 64, 64, 1, 256);
  rtg_head<<<512, 256, 0, stream>>>(hbuf, Wrtg, brtg, out_rtg);
}

// Round 21
// 1911.647 us; speedup vs baseline: 1.1415x; 1.0299x over previous
//
#include <hip/hip_runtime.h>
#include <hip/hip_bf16.h>

#define DI __device__ __forceinline__

typedef unsigned short u16;
typedef __bf16 bf16x8 __attribute__((ext_vector_type(8)));
typedef unsigned short u16x8 __attribute__((ext_vector_type(8)));
typedef unsigned short u16x4 __attribute__((ext_vector_type(4)));
typedef float f32x4 __attribute__((ext_vector_type(4)));

static constexpr int Bb = 8, Tt = 256, Hh = 1024, Ll = 6, NHd = 16, Dh = 64;
static constexpr int Ss = 3 * Tt;      // 768 tokens
static constexpr int FFd = 4096;
static constexpr int BSr = Bb * Ss;    // 6144 rows
static constexpr int QKVld = 3072;     // fused qkv row stride

DI u16 f2bf(float f) {
  unsigned u = __builtin_bit_cast(unsigned, f);
  u += 0x7fffu + ((u >> 16) & 1u);
  return (u16)(u >> 16);
}
DI float bf2f(u16 h) { return __builtin_bit_cast(float, (unsigned)h << 16); }

// tanh-form GELU (max |diff| vs erf-GELU ~3e-3, well under 7e-2 threshold)
DI float gelu_f(float x) {
  const float s = 1.5957691216f * x + 0.0713564814f * x * x * x;
  return x / (1.f + __expf(-s));
}

DI void gload_lds16(const u16* g, u16* l) {
  __builtin_amdgcn_global_load_lds((__attribute__((address_space(1))) void*)(g),
                                   (__attribute__((address_space(3))) void*)(l), 16, 0, 0);
}
DI bf16x8 ldl8(const u16* p) { return __builtin_bit_cast(bf16x8, *(const u16x8*)p); }
DI bf16x8 ldg8(const u16* p) { return __builtin_bit_cast(bf16x8, *(const u16x8*)p); }

DI void barRaw() {
  asm volatile("" ::: "memory");
  __builtin_amdgcn_s_barrier();
  asm volatile("" ::: "memory");
}

// ---------------------------------------------------------------------------
// GEMM: 128x128 tile, BK=64, 4 waves, double-buffered LDS (64 KiB, 2/CU).
// K-loop unrolled x2 static bases (R15); coalesced LDS-staged epilogue (R12,
// stride-130 C-tile); 2D-patch XCD swizzle (R13); tanh-GELU (R15); fused
// V-transpose for QKV (R18); bf16 outb path (R19).  [unchanged from R20]
// ---------------------------------------------------------------------------
__global__ __launch_bounds__(256, 2) void gemm_db(
    const u16* __restrict__ A, const u16* __restrict__ Bt,
    const float* __restrict__ bias, const float* __restrict__ bias2,
    const float* __restrict__ bias3,
    float* __restrict__ outf, u16* __restrict__ outb, u16* __restrict__ vt,
    int Kstride, int Ksub, int ldc, int act, size_t psz)
{
  __shared__ u16 SM[32768];   // 64 KiB: A0@0, A1@8192, B0@16384, B1@24576
  const int lane = threadIdx.x & 63, w = threadIdx.x >> 6;
  const int wr = w >> 1, wc = w & 1;
  const int l15 = lane & 15, l4 = lane >> 4;

  // bijective XCD swizzle (m204) + 2D patch mapping (CG=8 cols, bn fastest)
  const int gx = gridDim.x, gy = gridDim.y, nwg = gx * gy;
  int f = blockIdx.y * gx + blockIdx.x;
  { int q = nwg >> 3, rr = nwg & 7, x = f & 7, idx = f >> 3;
    f = (x < rr ? x * (q + 1) : rr * (q + 1) + (x - rr) * q) + idx; }
  const int r2 = f % (gy * 8), cg = f / (gy * 8);
  const int bm = r2 >> 3, bn = cg * 8 + (r2 & 7);
  const int koff = blockIdx.z * Ksub;
  const int NT = Ksub >> 6;   // even for all uses (16 / 64 / 16)

  const int srow = lane >> 3;
  const int schunk = ((lane & 7) ^ srow) << 3;
  unsigned aoff[4], boff[4];
#pragma unroll
  for (int i = 0; i < 4; ++i) {
    const int r = w * 32 + i * 8 + srow;
    aoff[i] = (unsigned)(bm * 128 + r) * (unsigned)Kstride + koff + schunk;
    boff[i] = (unsigned)(bn * 128 + r) * (unsigned)Kstride + koff + schunk;
  }

  auto stage = [&](int bsel, int kt) {
#pragma unroll
    for (int i = 0; i < 4; ++i)
      gload_lds16(A + aoff[i] + kt * 64, &SM[bsel * 8192 + (w * 32 + i * 8) * 64]);
#pragma unroll
    for (int i = 0; i < 4; ++i)
      gload_lds16(Bt + boff[i] + kt * 64, &SM[16384 + bsel * 8192 + (w * 32 + i * 8) * 64]);
  };

  f32x4 acc[4][4] = {};
  const int r7 = l15 & 7;

  auto body = [&](int CB, int tn, bool more) {
    if (more) stage(CB ^ 1, tn);
    bf16x8 af[4][2], bf[4][2];
#pragma unroll
    for (int m = 0; m < 4; ++m) {
#pragma unroll
      for (int kk = 0; kk < 2; ++kk) {
        const int slot = (((kk * 4 + l4) ^ r7) << 3);
        af[m][kk] = ldl8(&SM[CB * 8192 + (wr * 64 + m * 16 + l15) * 64 + slot]);
        bf[m][kk] = ldl8(&SM[16384 + CB * 8192 + (wc * 64 + m * 16 + l15) * 64 + slot]);
      }
    }
    __builtin_amdgcn_s_setprio(1);
#pragma unroll
    for (int kk = 0; kk < 2; ++kk)
#pragma unroll
      for (int m = 0; m < 4; ++m)
#pragma unroll
        for (int n = 0; n < 4; ++n)
          acc[m][n] = __builtin_amdgcn_mfma_f32_16x16x32_bf16(af[m][kk], bf[n][kk], acc[m][n], 0, 0, 0);
    __builtin_amdgcn_s_setprio(0);
    if (more) asm volatile("s_waitcnt vmcnt(0)" ::: "memory");  // aged drain
    barRaw();
  };

  stage(0, 0);
  asm volatile("s_waitcnt vmcnt(0)" ::: "memory");
  barRaw();

  for (int t = 0; t < NT; t += 2) {
    body(0, t + 1, t + 1 < NT);
    body(1, t + 2, t + 2 < NT);
  }

  // ---- coalesced epilogue via LDS staging (C-tile stride 130 u16) ----
  if (outb) {
#pragma unroll
    for (int n = 0; n < 4; ++n) {
      const int col = wc * 64 + n * 16 + l15;
      const int gcol = bn * 128 + col;
      float bval = 0.f;
      if (bias) {
        const float* bp_ = bias;
        int idx = gcol;
        if (bias2 && gcol >= 1024) { bp_ = (gcol >= 2048) ? bias3 : bias2; idx = gcol & 1023; }
        bval = bp_[idx];
      }
#pragma unroll
      for (int m = 0; m < 4; ++m) {
#pragma unroll
        for (int r = 0; r < 4; ++r) {
          const int lrow = wr * 64 + m * 16 + l4 * 4 + r;
          float x = acc[m][n][r] + bval;
          if (act) x = gelu_f(x);
          SM[lrow * 130 + col] = f2bf(x);
        }
      }
    }
    barRaw();
    if (vt && bn >= 16) {
      // V tile: write transposed into vt[B,NH,D,S].
      const int bb = bm / 6, s0 = (bm % 6) * 128;
      const int c = threadIdx.x & 127, sh = threadIdx.x >> 7;
      const int h2 = (bn - 16) * 2 + (c >> 6), d = c & 63;
      u16* dst = vt + ((size_t)(bb * NHd + h2) * Dh + d) * Ss + s0 + sh * 64;
#pragma unroll
      for (int jv = 0; jv < 8; ++jv) {
        u16x8 v8;
#pragma unroll
        for (int e = 0; e < 8; ++e)
          v8[e] = SM[(sh * 64 + jv * 8 + e) * 130 + c];
        *(u16x8*)&dst[jv * 8] = v8;
      }
    } else {
      u16* ob2 = outb + blockIdx.z * psz;
#pragma unroll 4
      for (int rr2 = 0; rr2 < 32; ++rr2) {
        const int row = rr2 * 4 + w;
        *(unsigned*)&ob2[(size_t)(bm * 128 + row) * ldc + bn * 128 + lane * 2] =
            *(const unsigned*)&SM[row * 130 + lane * 2];
      }
    }
  } else if (outf) {
    float* Cf = (float*)SM;
#pragma unroll
    for (int half = 0; half < 2; ++half) {
      barRaw();
      if (wr == half) {
#pragma unroll
        for (int n = 0; n < 4; ++n) {
          const int col = wc * 64 + n * 16 + l15;
          const int gcol = bn * 128 + col;
          float bval = 0.f;
          if (bias) {
            const float* bp_ = bias;
            int idx = gcol;
            if (bias2 && gcol >= 1024) { bp_ = (gcol >= 2048) ? bias3 : bias2; idx = gcol & 1023; }
            bval = bp_[idx];
          }
#pragma unroll
          for (int m = 0; m < 4; ++m) {
#pragma unroll
            for (int r = 0; r < 4; ++r) {
              float x = acc[m][n][r] + bval;
              if (act) x = gelu_f(x);
              Cf[(m * 16 + l4 * 4 + r) * 128 + col] = x;
            }
          }
        }
      }
      barRaw();
#pragma unroll 4
      for (int rr2 = 0; rr2 < 16; ++rr2) {
        const int row = rr2 * 4 + w;
        *(float2*)&outf[blockIdx.z * psz +
                        (size_t)(bm * 128 + half * 64 + row) * ldc + bn * 128 + lane * 2] =
            *(const float2*)&Cf[row * 128 + lane * 2];
      }
    }
  }
}

// ---------------------------------------------------------------------------
// Small GEMM (heads): 128x128 tile, BK=64, 4 waves, 16x16 MFMA.
// ---------------------------------------------------------------------------
__global__ __launch_bounds__(256, 2) void gemm_bf16(
    const u16* __restrict__ A, const u16* __restrict__ Bt,
    const float* __restrict__ bias, float* __restrict__ outf,
    int M, int N, int K, int ldc, int Nstore, int rowmode, int rowoff)
{
  __shared__ u16 As[128 * 64];
  __shared__ u16 Bs[128 * 64];
  const int tid = threadIdx.x;
  const int lane = tid & 63;
  const int w = tid >> 6;
  const int wr = w >> 1, wc = w & 1;
  const int bn = blockIdx.x, bm = blockIdx.y;
  const int l3 = lane >> 3, l7 = lane & 7, l15 = lane & 15, l4 = lane >> 4;

  f32x4 acc[4][4] = {};

  const int schunk = (l7 ^ l3) << 3;
  size_t aoff[4], boff[4];
#pragma unroll
  for (int i = 0; i < 4; ++i) {
    int r = bm * 128 + w * 32 + i * 8 + l3;
    int ar = rowmode ? ((r >> 8) * Ss + rowoff + (r & 255)) : r;
    aoff[i] = (size_t)ar * K + schunk;
    boff[i] = (size_t)(bn * 128 + w * 32 + i * 8 + l3) * K + schunk;
  }

  for (int kt = 0; kt < K; kt += 64) {
    __syncthreads();
#pragma unroll
    for (int i = 0; i < 4; ++i) {
      gload_lds16(A + aoff[i] + kt, &As[(w * 32 + i * 8) * 64]);
      gload_lds16(Bt + boff[i] + kt, &Bs[(w * 32 + i * 8) * 64]);
    }
    __syncthreads();

    bf16x8 af[4][2], bf[4][2];
#pragma unroll
    for (int m = 0; m < 4; ++m) {
#pragma unroll
      for (int kk = 0; kk < 2; ++kk) {
        const int slot = ((kk * 4 + l4) ^ l7) << 3;
        af[m][kk] = ldl8(&As[(wr * 64 + m * 16 + l15) * 64 + slot]);
        bf[m][kk] = ldl8(&Bs[(wc * 64 + m * 16 + l15) * 64 + slot]);
      }
    }
#pragma unroll
    for (int m = 0; m < 4; ++m)
#pragma unroll
      for (int n = 0; n < 4; ++n)
#pragma unroll
        for (int kk = 0; kk < 2; ++kk)
          acc[m][n] = __builtin_amdgcn_mfma_f32_16x16x32_bf16(af[m][kk], bf[n][kk], acc[m][n], 0, 0, 0);
  }

#pragma unroll
  for (int n = 0; n < 4; ++n) {
    const int col = bn * 128 + wc * 64 + n * 16 + l15;
    const bool cok = col < Nstore;
    const float bv = (cok && bias) ? bias[col] : 0.f;
#pragma unroll
    for (int m = 0; m < 4; ++m) {
#pragma unroll
      for (int r = 0; r < 4; ++r) {
        const int row = bm * 128 + wr * 64 + m * 16 + l4 * 4 + r;
        if (cok) outf[(size_t)row * ldc + col] = acc[m][n][r] + bv;
      }
    }
  }
}

// ---------------------------------------------------------------------------
// Flash attention (unchanged)
// ---------------------------------------------------------------------------
__global__ __launch_bounds__(256, 3) void attn_flash(
    const u16* __restrict__ qkv, const u16* __restrict__ vt, u16* __restrict__ o)
{
  __shared__ u16 Kl[2][64 * 64];
  __shared__ u16 Vl[2][64 * 64];
  __shared__ u16 Pl[4][16 * 64];
  const int qt = blockIdx.x, h = blockIdx.y, b = blockIdx.z;
  const int lane = threadIdx.x & 63, w = threadIdx.x >> 6;
  const int l15 = lane & 15, l4 = lane >> 4;

  const size_t qoff = (size_t)(b * Ss + qt * 64 + w * 16 + l15) * QKVld + h * Dh + l4 * 8;
  const bf16x8 aq0 = ldg8(qkv + qoff), aq1 = ldg8(qkv + qoff + 32);

  const u16* kg = qkv + (size_t)b * Ss * QKVld + 1024 + h * Dh;
  const u16* vg = vt + (size_t)(b * NHd + h) * Dh * Ss;

  int srow[2], scs[2];
#pragma unroll
  for (int i = 0; i < 2; ++i) {
    srow[i] = (w * 2 + i) * 8 + (lane >> 3);
    scs[i] = ((lane & 7) ^ (srow[i] & 7)) * 8;
  }

  float m[4] = {-1e30f, -1e30f, -1e30f, -1e30f};
  float lsum[4] = {0.f, 0.f, 0.f, 0.f};
  f32x4 oa[4] = {};

  auto stage = [&](int bsel, int kb) {
#pragma unroll
    for (int i = 0; i < 2; ++i) {
      gload_lds16(kg + (size_t)(kb * 64 + srow[i]) * QKVld + scs[i], &Kl[bsel][(w * 2 + i) * 8 * 64]);
      gload_lds16(vg + (size_t)srow[i] * Ss + kb * 64 + scs[i], &Vl[bsel][(w * 2 + i) * 8 * 64]);
    }
  };

  stage(0, 0);
  __syncthreads();
  int buf = 0;
  for (int kb = 0; kb <= qt; ++kb) {
    if (kb < qt) stage(buf ^ 1, kb + 1);

    f32x4 sc[4];
    __builtin_amdgcn_s_setprio(1);
#pragma unroll
    for (int fj = 0; fj < 4; ++fj) {
      const u16* kp = &Kl[buf][(fj * 16 + l15) * 64];
      const int r7 = l15 & 7;
      bf16x8 kf0 = ldl8(kp + ((l4 ^ r7) << 3));
      bf16x8 kf1 = ldl8(kp + (((4 + l4) ^ r7) << 3));
      f32x4 zz = {};
      zz = __builtin_amdgcn_mfma_f32_16x16x32_bf16(aq0, kf0, zz, 0, 0, 0);
      sc[fj] = __builtin_amdgcn_mfma_f32_16x16x32_bf16(aq1, kf1, zz, 0, 0, 0);
    }
    __builtin_amdgcn_s_setprio(0);

    float pm[4] = {-1e30f, -1e30f, -1e30f, -1e30f};
    const bool diag = (kb == qt);
#pragma unroll
    for (int fj = 0; fj < 4; ++fj)
#pragma unroll
      for (int r = 0; r < 4; ++r) {
        float s = sc[fj][r] * 0.125f;
        if (diag && (fj * 16 + l15) > (w * 16 + l4 * 4 + r)) s = -1e30f;
        sc[fj][r] = s;
        pm[r] = fmaxf(pm[r], s);
      }
#pragma unroll
    for (int d = 1; d < 16; d <<= 1)
#pragma unroll
      for (int r = 0; r < 4; ++r) pm[r] = fmaxf(pm[r], __shfl_xor(pm[r], d));

    float al[4], ps[4];
#pragma unroll
    for (int r = 0; r < 4; ++r) {
      float mn = fmaxf(m[r], pm[r]);
      al[r] = __expf(m[r] - mn);
      m[r] = mn;
      ps[r] = 0.f;
    }
#pragma unroll
    for (int fj = 0; fj < 4; ++fj)
#pragma unroll
      for (int r = 0; r < 4; ++r) {
        float p = __expf(sc[fj][r] - m[r]);
        sc[fj][r] = p;
        ps[r] += p;
      }
#pragma unroll
    for (int d = 1; d < 16; d <<= 1)
#pragma unroll
      for (int r = 0; r < 4; ++r) ps[r] += __shfl_xor(ps[r], d);
#pragma unroll
    for (int r = 0; r < 4; ++r) lsum[r] = lsum[r] * al[r] + ps[r];
#pragma unroll
    for (int fn = 0; fn < 4; ++fn)
#pragma unroll
      for (int r = 0; r < 4; ++r) oa[fn][r] *= al[r];

#pragma unroll
    for (int fj = 0; fj < 4; ++fj)
#pragma unroll
      for (int r = 0; r < 4; ++r) {
        const int key = fj * 16 + l15, qloc = l4 * 4 + r;
        Pl[w][qloc * 64 + (((key >> 3) ^ (qloc & 7)) << 3) + (key & 7)] = f2bf(sc[fj][r]);
      }

    const int q7 = l15 & 7;
    bf16x8 pa0 = ldl8(&Pl[w][l15 * 64 + ((l4 ^ q7) << 3)]);
    bf16x8 pa1 = ldl8(&Pl[w][l15 * 64 + (((4 + l4) ^ q7) << 3)]);
    __builtin_amdgcn_s_setprio(1);
#pragma unroll
    for (int fn = 0; fn < 4; ++fn) {
      const u16* vp = &Vl[buf][(fn * 16 + l15) * 64];
      bf16x8 vf0 = ldl8(vp + ((l4 ^ q7) << 3));
      bf16x8 vf1 = ldl8(vp + (((4 + l4) ^ q7) << 3));
      oa[fn] = __builtin_amdgcn_mfma_f32_16x16x32_bf16(pa0, vf0, oa[fn], 0, 0, 0);
      oa[fn] = __builtin_amdgcn_mfma_f32_16x16x32_bf16(pa1, vf1, oa[fn], 0, 0, 0);
    }
    __builtin_amdgcn_s_setprio(0);
    __syncthreads();
    buf ^= 1;
  }

#pragma unroll
  for (int fn = 0; fn < 4; ++fn)
#pragma unroll
    for (int r = 0; r < 4; ++r) {
      const int row = b * Ss + qt * 64 + w * 16 + l4 * 4 + r;
      o[(size_t)row * Hh + h * Dh + fn * 16 + l15] = f2bf(oa[fn][r] / lsum[r]);
    }
}

// ---------------------------------------------------------------------------
// Embedding + interleave + LayerNorm -> x (bf16 residual stream, R21)
// ---------------------------------------------------------------------------
__global__ __launch_bounds__(256) void embed_ln(
    const int* __restrict__ timesteps, const int* __restrict__ states,
    const int* __restrict__ actions, const float* __restrict__ rtg,
    const float* __restrict__ Wt, const float* __restrict__ Ws,
    const float* __restrict__ Wa, const float* __restrict__ Wr,
    const float* __restrict__ br, const float* __restrict__ lng,
    const float* __restrict__ lnb, u16* __restrict__ xb)
{
  __shared__ float red[8];
  const int s = blockIdx.x;
  const int b = s / Ss, sl = s % Ss;
  const int tt = sl / 3, kind = sl % 3;
  const int bt = b * Tt + tt;
  const int e = threadIdx.x * 4;

  const float4 tv = *(const float4*)(Wt + (size_t)timesteps[bt] * Hh + e);
  float v[4];
  if (kind == 0) {
    const float rr = rtg[bt];
    const float4 w4 = *(const float4*)(Wr + e);
    const float4 b4 = *(const float4*)(br + e);
    v[0] = rr * w4.x + b4.x + tv.x; v[1] = rr * w4.y + b4.y + tv.y;
    v[2] = rr * w4.z + b4.z + tv.z; v[3] = rr * w4.w + b4.w + tv.w;
  } else {
    const float* emb = (kind == 1) ? (Ws + (size_t)states[bt] * Hh)
                                   : (Wa + (size_t)actions[bt] * Hh);
    const float4 e4 = *(const float4*)(emb + e);
    v[0] = e4.x + tv.x; v[1] = e4.y + tv.y; v[2] = e4.z + tv.z; v[3] = e4.w + tv.w;
  }
  float s1 = v[0] + v[1] + v[2] + v[3];
  float s2 = v[0]*v[0] + v[1]*v[1] + v[2]*v[2] + v[3]*v[3];
#pragma unroll
  for (int d = 32; d; d >>= 1) { s1 += __shfl_xor(s1, d); s2 += __shfl_xor(s2, d); }
  if ((threadIdx.x & 63) == 0) { red[threadIdx.x >> 6] = s1; red[4 + (threadIdx.x >> 6)] = s2; }
  __syncthreads();
  s1 = red[0] + red[1] + red[2] + red[3];
  s2 = red[4] + red[5] + red[6] + red[7];
  const float mean = s1 * (1.f / 1024.f);
  const float var = s2 * (1.f / 1024.f) - mean * mean;
  const float rs = rsqrtf(var + 1e-5f);
  const float4 g4 = *(const float4*)(lng + e);
  const float4 bb4 = *(const float4*)(lnb + e);
  float o0 = (v[0] - mean) * rs * g4.x + bb4.x;
  float o1 = (v[1] - mean) * rs * g4.y + bb4.y;
  float o2 = (v[2] - mean) * rs * g4.z + bb4.z;
  float o3 = (v[3] - mean) * rs * g4.w + bb4.w;
  u16x4 ov = {f2bf(o0), f2bf(o1), f2bf(o2), f2bf(o3)};
  *(u16x4*)(xb + (size_t)s * Hh + e) = ov;
}

// ---------------------------------------------------------------------------
// LayerNorm (R21: bf16 residual stream): v = bf(pA)+bf(pB?)+bf(resid)+bias;
// writes only xb (the bf16 residual/LN stream). resid may alias xb (same-row
// read-before-write, no cross-thread overlap).
// ---------------------------------------------------------------------------
__global__ __launch_bounds__(256) void ln_kernel(
    const u16* __restrict__ pA, const u16* __restrict__ pB,
    const u16* __restrict__ resid, const float* __restrict__ bias,
    const float* __restrict__ g, const float* __restrict__ bta,
    u16* __restrict__ xb)
{
  __shared__ float red[8];
  const int row = blockIdx.x;
  const int e = threadIdx.x * 4;
  const u16x4 a4 = *(const u16x4*)(pA + (size_t)row * Hh + e);
  float v[4] = {bf2f(a4[0]), bf2f(a4[1]), bf2f(a4[2]), bf2f(a4[3])};
  if (pB) {
    const u16x4 b4 = *(const u16x4*)(pB + (size_t)row * Hh + e);
    v[0] += bf2f(b4[0]); v[1] += bf2f(b4[1]); v[2] += bf2f(b4[2]); v[3] += bf2f(b4[3]);
  }
  {
    const u16x4 r4 = *(const u16x4*)(resid + (size_t)row * Hh + e);
    v[0] += bf2f(r4[0]); v[1] += bf2f(r4[1]); v[2] += bf2f(r4[2]); v[3] += bf2f(r4[3]);
  }
  if (bias) {
    const float4 c4 = *(const float4*)(bias + e);
    v[0] += c4.x; v[1] += c4.y; v[2] += c4.z; v[3] += c4.w;
  }
  float s1 = v[0] + v[1] + v[2] + v[3];
  float s2 = v[0]*v[0] + v[1]*v[1] + v[2]*v[2] + v[3]*v[3];
#pragma unroll
  for (int d = 32; d; d >>= 1) { s1 += __shfl_xor(s1, d); s2 += __shfl_xor(s2, d); }
  if ((threadIdx.x & 63) == 0) { red[threadIdx.x >> 6] = s1; red[4 + (threadIdx.x >> 6)] = s2; }
  __syncthreads();
  s1 = red[0] + red[1] + red[2] + red[3];
  s2 = red[4] + red[5] + red[6] + red[7];
  const float mean = s1 * (1.f / 1024.f);
  const float var = s2 * (1.f / 1024.f) - mean * mean;
  const float rs = rsqrtf(var + 1e-5f);
  const float4 g4 = *(const float4*)(g + e);
  const float4 b4 = *(const float4*)(bta + e);
  float o0 = (v[0] - mean) * rs * g4.x + b4.x;
  float o1 = (v[1] - mean) * rs * g4.y + b4.y;
  float o2 = (v[2] - mean) * rs * g4.z + b4.z;
  float o3 = (v[3] - mean) * rs * g4.w + b4.w;
  u16x4 ov = {f2bf(o0), f2bf(o1), f2bf(o2), f2bf(o3)};
  *(u16x4*)(xb + (size_t)row * Hh + e) = ov;
}

// W [Kd,Nd] fp32  ->  Wt [Nout,Kd] bf16 (rows >= Nd zero-padded)
__global__ __launch_bounds__(256) void transpose_w(
    const float* __restrict__ W, u16* __restrict__ Wt, int Kd, int Nd, int Nout)
{
  __shared__ float tile[32][33];
  const int k0 = blockIdx.x * 32, n0 = blockIdx.y * 32;
  const int tx = threadIdx.x & 31, ty = threadIdx.x >> 5;
#pragma unroll
  for (int rr = 0; rr < 4; ++rr) {
    const int kk = ty + rr * 8;
    const int n = n0 + tx;
    tile[kk][tx] = (n < Nd) ? W[(size_t)(k0 + kk) * Nd + n] : 0.f;
  }
  __syncthreads();
#pragma unroll
  for (int rr = 0; rr < 4; ++rr) {
    Wt[(size_t)(n0 + ty + rr * 8) * Kd + k0 + tx] = f2bf(tile[tx][ty + rr * 8]);
  }
}

// ---------------------------------------------------------------------------
// Fused per-layer weight transpose: all 6 matrices in ONE launch (R16).
// ---------------------------------------------------------------------------
__global__ __launch_bounds__(256) void transpose_all(
    const float* __restrict__ Wq, const float* __restrict__ Wk,
    const float* __restrict__ Wv, const float* __restrict__ Wp,
    const float* __restrict__ W1, const float* __restrict__ W2,
    u16* __restrict__ W3T, u16* __restrict__ WpT,
    u16* __restrict__ W1T, u16* __restrict__ W2T)
{
  __shared__ float tile[32][33];
  const int t = blockIdx.x;
  const float* src;
  u16* dst;
  int Kd, Nd, ti;
  if (t < 4096) {
    const int which = t >> 10;
    ti = t & 1023;
    Kd = 1024; Nd = 1024;
    src = (which == 0) ? Wq : (which == 1) ? Wk : (which == 2) ? Wv : Wp;
    dst = (which == 3) ? WpT : (W3T + (size_t)which * 1024 * 1024);
  } else if (t < 8192) {
    ti = t - 4096; Kd = 1024; Nd = 4096; src = W1; dst = W1T;
  } else {
    ti = t - 8192; Kd = 4096; Nd = 1024; src = W2; dst = W2T;
  }
  const int tilesK = Kd >> 5;
  const int k0 = (ti % tilesK) * 32, n0 = (ti / tilesK) * 32;
  const int tx = threadIdx.x & 31, ty = threadIdx.x >> 5;
#pragma unroll
  for (int rr = 0; rr < 4; ++rr) {
    const int kk = ty + rr * 8;
    tile[kk][tx] = src[(size_t)(k0 + kk) * Nd + n0 + tx];
  }
  __syncthreads();
#pragma unroll
  for (int rr = 0; rr < 4; ++rr) {
    dst[(size_t)(n0 + ty + rr * 8) * Kd + k0 + tx] = f2bf(tile[tx][ty + rr * 8]);
  }
}

// rtg head (R21: reads bf16 residual stream)
__global__ __launch_bounds__(256) void rtg_head(
    const u16* __restrict__ x, const float* __restrict__ Wr1,
    const float* __restrict__ br1, float* __restrict__ out)
{
  const int lane = threadIdx.x & 63, w = threadIdx.x >> 6;
  const int row = blockIdx.x * 4 + w;
  const int b = row >> 8, tt = row & 255;
  const u16* xr = x + (size_t)(b * Ss + 512 + tt) * Hh;
  float s = 0.f;
  for (int e = lane; e < Hh; e += 64) s += bf2f(xr[e]) * Wr1[e];
#pragma unroll
  for (int d = 32; d; d >>= 1) s += __shfl_xor(s, d);
  if (lane == 0) out[row] = s + br1[0];
}

// ---------------------------------------------------------------------------
extern "C" void kernel_launch(void* const* d_in, const int* in_sizes, int n_in,
                              void* d_out, int out_size, void* d_ws, size_t ws_size,
                              hipStream_t stream)
{
  (void)in_sizes; (void)n_in; (void)out_size; (void)ws_size;
  const int*   timesteps = (const int*)d_in[0];
  const int*   states    = (const int*)d_in[1];
  const int*   actions   = (const int*)d_in[2];
  const float* rtg       = (const float*)d_in[3];
  const float* Wt   = (const float*)d_in[4];
  const float* Ws   = (const float*)d_in[5];
  const float* Wa   = (const float*)d_in[6];
  const float* Wr   = (const float*)d_in[7];
  const float* br   = (const float*)d_in[8];
  const float* lng  = (const float*)d_in[9];
  const float* lnb  = (const float*)d_in[10];
  const float* Wq   = (const float*)d_in[11];
  const float* bq   = (const float*)d_in[12];
  const float* Wk   = (const float*)d_in[13];
  const float* bk   = (const float*)d_in[14];
  const float* Wv   = (const float*)d_in[15];
  const float* bv   = (const float*)d_in[16];
  const float* Wp   = (const float*)d_in[17];
  const float* bp   = (const float*)d_in[18];
  const float* W1   = (const float*)d_in[19];
  const float* b1   = (const float*)d_in[20];
  const float* W2   = (const float*)d_in[21];
  const float* b2   = (const float*)d_in[22];
  const float* ln1g = (const float*)d_in[23];
  const float* ln1b = (const float*)d_in[24];
  const float* ln2g = (const float*)d_in[25];
  const float* ln2b = (const float*)d_in[26];
  const float* Wrtg = (const float*)d_in[27];
  const float* brtg = (const float*)d_in[28];
  const float* Wst  = (const float*)d_in[29];
  const float* bst  = (const float*)d_in[30];
  const float* Wac  = (const float*)d_in[31];
  const float* bac  = (const float*)d_in[32];

  char* wp = (char*)d_ws;
  auto alloc = [&](size_t bytes) { void* p = wp; wp += (bytes + 511) & ~(size_t)511; return p; };
  u16* pb   = (u16*)alloc((size_t)BSr * Hh * 2);   // bf16 GEMM output
  u16* xb   = (u16*)alloc((size_t)BSr * Hh * 2);   // bf16 residual/LN stream
  u16* qkvb = (u16*)alloc((size_t)BSr * QKVld * 2);
  u16* vtb  = (u16*)alloc((size_t)BSr * Hh * 2);
  u16* ob   = (u16*)alloc((size_t)BSr * Hh * 2);
  u16* ub   = (u16*)alloc((size_t)BSr * FFd * 2);
  u16* W3T  = (u16*)alloc((size_t)3 * Hh * Hh * 2);
  u16* WpT  = (u16*)alloc((size_t)Hh * Hh * 2);
  u16* W1T  = (u16*)alloc((size_t)FFd * Hh * 2);
  u16* W2T  = (u16*)alloc((size_t)Hh * FFd * 2);
  u16* WstT = (u16*)alloc((size_t)Hh * Hh * 2);
  u16* WacT = (u16*)alloc((size_t)128 * Hh * 2);

  float* out_state = (float*)d_out;
  float* out_act   = out_state + (size_t)2048 * 1024;
  float* out_rtg   = out_act + (size_t)2048 * 64;

  transpose_w<<<dim3(32, 32, 1), 256, 0, stream>>>(Wst, WstT, 1024, 1024, 1024);
  transpose_w<<<dim3(32, 4, 1), 256, 0, stream>>>(Wac, WacT, 1024, 64, 128);
  embed_ln<<<BSr, 256, 0, stream>>>(timesteps, states, actions, rtg, Wt, Ws, Wa, Wr,
                                    br, lng, lnb, xb);

  for (int l = 0; l < Ll; ++l) {
    transpose_all<<<12288, 256, 0, stream>>>(
        Wq + (size_t)l * Hh * Hh, Wk + (size_t)l * Hh * Hh,
        Wv + (size_t)l * Hh * Hh, Wp + (size_t)l * Hh * Hh,
        W1 + (size_t)l * Hh * FFd, W2 + (size_t)l * FFd * Hh,
        W3T, WpT, W1T, W2T);

    // fused QKV: [6144,1024] x [1024,3072] -> qkvb (Q,K) + vtb (V transposed)
    gemm_db<<<dim3(24, 48, 1), 256, 0, stream>>>(
        xb, W3T, bq + l * Hh, bk + l * Hh, bv + l * Hh, nullptr, qkvb, vtb,
        Hh, Hh, QKVld, 0, 0);
    attn_flash<<<dim3(12, 16, 8), 256, 0, stream>>>(qkvb, vtb, ob);
    // attn out projection: bf16 -> pb
    gemm_db<<<dim3(8, 48, 1), 256, 0, stream>>>(
        ob, WpT, nullptr, nullptr, nullptr, nullptr, pb, nullptr,
        Hh, Hh, Hh, 0, 0);
    ln_kernel<<<BSr, 256, 0, stream>>>(pb, nullptr, xb, bp + l * Hh,
                                       ln1g + l * Hh, ln1b + l * Hh, xb);
    // FFN1: [6144,1024] x [1024,4096], GELU -> ub bf16
    gemm_db<<<dim3(32, 48, 1), 256, 0, stream>>>(
        xb, W1T, b1 + l * FFd, nullptr, nullptr, nullptr, ub, nullptr,
        Hh, Hh, FFd, 1, 0);
    // FFN2: [6144,4096] x [4096,1024]: bf16 -> pb
    gemm_db<<<dim3(8, 48, 1), 256, 0, stream>>>(
        ub, W2T, nullptr, nullptr, nullptr, nullptr, pb, nullptr,
        FFd, FFd, Hh, 0, 0);
    ln_kernel<<<BSr, 256, 0, stream>>>(pb, nullptr, xb, b2 + l * Hh,
                                       ln2g + l * Hh, ln2b + l * Hh, xb);
  }

  gemm_bf16<<<dim3(8, 16), 256, 0, stream>>>(xb, WstT, bst, out_state,
                                             2048, 1024, 1024, 1024, 1024, 1, 512);
  gemm_bf16<<<dim3(1, 16), 256, 0, stream>>>(xb, WacT, bac, out_act,
                                             2048, 128, 1024, 64, 64, 1, 256);
  rtg_head<<<512, 256, 0, stream>>>(xb, Wrtg, brtg, out_rtg);
}